// Round 1
// baseline (5714.470 us; speedup 1.0000x reference)
//
#include <hip/hip_runtime.h>

constexpr int D = 128;

// ---------------------------------------------------------------------------
// Transpose the 4 weight matrices [j][k] -> [k][j] so GEMM B-loads stream.
__global__ __launch_bounds__(256) void transpose_w(
    const float* __restrict__ w1l, const float* __restrict__ w1r,
    const float* __restrict__ w2l, const float* __restrict__ w2r,
    float* __restrict__ out)
{
    int b = blockIdx.y;
    const float* src = (b == 0) ? w1l : (b == 1) ? w1r : (b == 2) ? w2l : w2r;
    int idx = blockIdx.x * 256 + threadIdx.x;   // 0..16383 (grid.x = 64)
    int k = idx >> 7;
    int j = idx & 127;
    out[b * 16384 + idx] = src[j * D + k];
}

// ---------------------------------------------------------------------------
// Edge-parallel scatter-add: agg[dst] += feat[src]; optionally deg[dst] += 1.
// 32 threads per edge, float4 per thread.
__global__ __launch_bounds__(256) void scatter_kernel(
    const float* __restrict__ feat, const int* __restrict__ srcI,
    const int* __restrict__ dstI, float* __restrict__ agg,
    float* __restrict__ deg, int E)
{
    int t = blockIdx.x * 256 + threadIdx.x;
    int e = t >> 5;
    if (e >= E) return;
    int lane = t & 31;
    int s = srcI[e];
    int d = dstI[e];
    const float4 v = *reinterpret_cast<const float4*>(feat + (size_t)s * D + lane * 4);
    float* a = agg + (size_t)d * D + lane * 4;
    atomicAdd(a + 0, v.x);
    atomicAdd(a + 1, v.y);
    atomicAdd(a + 2, v.z);
    atomicAdd(a + 3, v.w);
    if (deg != nullptr && lane == 0) atomicAdd(deg + d, 1.0f);
}

// ---------------------------------------------------------------------------
// Fused SAGE layer: out[i][j] = relu( (agg[i]/max(deg[i],1)) @ WtL[:,j] + bL[j]
//                                     + xin[i] @ WtR[:,j] )
// Block: 256 threads, 64 nodes x 128 cols. Thread: 4 rows x 8 cols.
// outbuf may alias aggbuf (rows staged to LDS before any write).
__global__ __launch_bounds__(256) void fused_gemm(
    const float* __restrict__ aggbuf,   // [n][128] summed neighbor feats
    const float* __restrict__ deg,      // [n]
    const float* __restrict__ xin,      // [n][128] self feats
    const float* __restrict__ wtL,      // [128][128] (k-major)
    const float* __restrict__ wtR,      // [128][128] (k-major)
    const float* __restrict__ bL,       // [128]
    float* __restrict__ outbuf,         // [n][128]
    int n)
{
    __shared__ float aTile[64 * D];     // 32 KiB
    __shared__ float invdeg[64];

    const int tid = threadIdx.x;
    const int node0 = blockIdx.x * 64;
    const int ng = tid & 15;            // col group: j0 = ng*8
    const int mg = tid >> 4;            // row group: rows mg*4 .. mg*4+3
    const int j0 = ng * 8;

    if (tid < 64) {
        int row = node0 + tid;
        float dg = (row < n) ? deg[row] : 1.0f;
        invdeg[tid] = 1.0f / fmaxf(dg, 1.0f);
    }
    __syncthreads();

    float acc[4][8];
#pragma unroll
    for (int m = 0; m < 4; ++m)
#pragma unroll
        for (int c = 0; c < 8; ++c) acc[m][c] = 0.0f;

    for (int p = 0; p < 2; ++p) {
        const float* A = p ? xin : aggbuf;
        const float* W = p ? wtR : wtL;

        // Stage 64x128 A-tile (apply 1/deg for the mean pass).
#pragma unroll
        for (int it = 0; it < 8; ++it) {
            int idx = tid + it * 256;          // 0..2047 float4 slots
            int r = idx >> 5;
            int c = idx & 31;
            int row = node0 + r;
            float4 v = make_float4(0.f, 0.f, 0.f, 0.f);
            if (row < n)
                v = *reinterpret_cast<const float4*>(A + (size_t)row * D + c * 4);
            if (p == 0) {
                float sI = invdeg[r];
                v.x *= sI; v.y *= sI; v.z *= sI; v.w *= sI;
            }
            *reinterpret_cast<float4*>(&aTile[r * D + c * 4]) = v;
        }
        __syncthreads();

        const float4* W4 = reinterpret_cast<const float4*>(W);
        const float4* aT4 = reinterpret_cast<const float4*>(aTile);

        for (int k4 = 0; k4 < 32; ++k4) {
            const float4 a0 = aT4[(mg * 4 + 0) * 32 + k4];
            const float4 a1 = aT4[(mg * 4 + 1) * 32 + k4];
            const float4 a2 = aT4[(mg * 4 + 2) * 32 + k4];
            const float4 a3 = aT4[(mg * 4 + 3) * 32 + k4];
#pragma unroll
            for (int kk = 0; kk < 4; ++kk) {
                const int k = k4 * 4 + kk;
                const float4 w0 = W4[k * 32 + ng * 2 + 0];
                const float4 w1 = W4[k * 32 + ng * 2 + 1];
                const float am0 = (kk == 0) ? a0.x : (kk == 1) ? a0.y : (kk == 2) ? a0.z : a0.w;
                const float am1 = (kk == 0) ? a1.x : (kk == 1) ? a1.y : (kk == 2) ? a1.z : a1.w;
                const float am2 = (kk == 0) ? a2.x : (kk == 1) ? a2.y : (kk == 2) ? a2.z : a2.w;
                const float am3 = (kk == 0) ? a3.x : (kk == 1) ? a3.y : (kk == 2) ? a3.z : a3.w;
                acc[0][0] += am0 * w0.x; acc[0][1] += am0 * w0.y;
                acc[0][2] += am0 * w0.z; acc[0][3] += am0 * w0.w;
                acc[0][4] += am0 * w1.x; acc[0][5] += am0 * w1.y;
                acc[0][6] += am0 * w1.z; acc[0][7] += am0 * w1.w;
                acc[1][0] += am1 * w0.x; acc[1][1] += am1 * w0.y;
                acc[1][2] += am1 * w0.z; acc[1][3] += am1 * w0.w;
                acc[1][4] += am1 * w1.x; acc[1][5] += am1 * w1.y;
                acc[1][6] += am1 * w1.z; acc[1][7] += am1 * w1.w;
                acc[2][0] += am2 * w0.x; acc[2][1] += am2 * w0.y;
                acc[2][2] += am2 * w0.z; acc[2][3] += am2 * w0.w;
                acc[2][4] += am2 * w1.x; acc[2][5] += am2 * w1.y;
                acc[2][6] += am2 * w1.z; acc[2][7] += am2 * w1.w;
                acc[3][0] += am3 * w0.x; acc[3][1] += am3 * w0.y;
                acc[3][2] += am3 * w0.z; acc[3][3] += am3 * w0.w;
                acc[3][4] += am3 * w1.x; acc[3][5] += am3 * w1.y;
                acc[3][6] += am3 * w1.z; acc[3][7] += am3 * w1.w;
            }
        }
        __syncthreads();
    }

    // Epilogue: + bias, relu, store.
    const float4 bl0 = *reinterpret_cast<const float4*>(bL + j0);
    const float4 bl1 = *reinterpret_cast<const float4*>(bL + j0 + 4);
#pragma unroll
    for (int m = 0; m < 4; ++m) {
        int row = node0 + mg * 4 + m;
        if (row < n) {
            float4 o0, o1;
            o0.x = fmaxf(acc[m][0] + bl0.x, 0.f);
            o0.y = fmaxf(acc[m][1] + bl0.y, 0.f);
            o0.z = fmaxf(acc[m][2] + bl0.z, 0.f);
            o0.w = fmaxf(acc[m][3] + bl0.w, 0.f);
            o1.x = fmaxf(acc[m][4] + bl1.x, 0.f);
            o1.y = fmaxf(acc[m][5] + bl1.y, 0.f);
            o1.z = fmaxf(acc[m][6] + bl1.z, 0.f);
            o1.w = fmaxf(acc[m][7] + bl1.w, 0.f);
            *reinterpret_cast<float4*>(outbuf + (size_t)row * D + j0) = o0;
            *reinterpret_cast<float4*>(outbuf + (size_t)row * D + j0 + 4) = o1;
        }
    }
}

// ---------------------------------------------------------------------------
// out[i][d] = sum_j h2[i][j] * w_out[d][j] + b_out[d]   (d_out = 4)
// 32 threads per node; half-wave shuffle reduction.
__global__ __launch_bounds__(256) void out_proj(
    const float* __restrict__ h2, const float* __restrict__ w_out,
    const float* __restrict__ b_out, float* __restrict__ out, int n)
{
    __shared__ float wsm[4 * D];
    wsm[threadIdx.x] = w_out[threadIdx.x];
    wsm[threadIdx.x + 256] = w_out[threadIdx.x + 256];
    __syncthreads();

    int t = blockIdx.x * 256 + threadIdx.x;
    int i = t >> 5;
    if (i >= n) return;
    int lane = t & 31;

    const float4 h = *reinterpret_cast<const float4*>(h2 + (size_t)i * D + lane * 4);
    float p[4];
#pragma unroll
    for (int d = 0; d < 4; ++d) {
        const float* wr = &wsm[d * D + lane * 4];
        p[d] = h.x * wr[0] + h.y * wr[1] + h.z * wr[2] + h.w * wr[3];
    }
#pragma unroll
    for (int off = 16; off > 0; off >>= 1) {
#pragma unroll
        for (int d = 0; d < 4; ++d) p[d] += __shfl_down(p[d], off, 32);
    }
    if (lane == 0) {
        const float4 b = *reinterpret_cast<const float4*>(b_out);
        float4 o;
        o.x = p[0] + b.x; o.y = p[1] + b.y; o.z = p[2] + b.z; o.w = p[3] + b.w;
        *reinterpret_cast<float4*>(out + (size_t)i * 4) = o;
    }
}

// ---------------------------------------------------------------------------
extern "C" void kernel_launch(void* const* d_in, const int* in_sizes, int n_in,
                              void* d_out, int out_size, void* d_ws, size_t ws_size,
                              hipStream_t stream)
{
    const float* x    = (const float*)d_in[0];
    const int*   ei   = (const int*)  d_in[1];
    const float* w1l  = (const float*)d_in[2];
    const float* b1l  = (const float*)d_in[3];
    const float* w1r  = (const float*)d_in[4];
    const float* w2l  = (const float*)d_in[5];
    const float* b2l  = (const float*)d_in[6];
    const float* w2r  = (const float*)d_in[7];
    const float* wout = (const float*)d_in[8];
    const float* bout = (const float*)d_in[9];

    const int n = in_sizes[0] / D;       // 100000
    const int E = in_sizes[1] / 2;       // 1600000
    const int* srcI = ei;
    const int* dstI = ei + E;

    float* ws   = (float*)d_ws;
    float* deg  = ws;                          // [n]
    float* bufA = ws + n;                      // [n][128]  agg1 -> h1 (in place)
    float* bufB = bufA + (size_t)n * D;        // [n][128]  agg2 -> h2 (in place)
    float* wt   = bufB + (size_t)n * D;        // 4 x [128][128] transposed weights

    // Zero deg + bufA + bufB (ws is poisoned before every timed launch).
    hipMemsetAsync(deg, 0, sizeof(float) * ((size_t)n * (2 * D + 1)), stream);

    dim3 tgrid(64, 4);
    transpose_w<<<tgrid, 256, 0, stream>>>(w1l, w1r, w2l, w2r, wt);

    const int sblocks = (int)(((long long)E * 32 + 255) / 256);
    const int gblocks = (n + 63) / 64;

    // Layer 1
    scatter_kernel<<<sblocks, 256, 0, stream>>>(x, srcI, dstI, bufA, deg, E);
    fused_gemm<<<gblocks, 256, 0, stream>>>(bufA, deg, x, wt, wt + 16384, b1l, bufA, n);

    // Layer 2
    scatter_kernel<<<sblocks, 256, 0, stream>>>(bufA, srcI, dstI, bufB, nullptr, E);
    fused_gemm<<<gblocks, 256, 0, stream>>>(bufB, deg, bufA, wt + 2 * 16384, wt + 3 * 16384, b2l, bufB, n);

    // Output projection
    const int oblocks = (int)(((long long)n * 32 + 255) / 256);
    out_proj<<<oblocks, 256, 0, stream>>>(bufB, wout, bout, (float*)d_out, n);
}

// Round 2
// 995.294 us; speedup vs baseline: 5.7415x; 5.7415x over previous
//
#include <hip/hip_runtime.h>

constexpr int D = 128;

// ---------------------------------------------------------------------------
// Transpose the 4 weight matrices [j][k] -> [k][j] so GEMM B-loads stream.
__global__ __launch_bounds__(256) void transpose_w(
    const float* __restrict__ w1l, const float* __restrict__ w1r,
    const float* __restrict__ w2l, const float* __restrict__ w2r,
    float* __restrict__ out)
{
    int b = blockIdx.y;
    const float* src = (b == 0) ? w1l : (b == 1) ? w1r : (b == 2) ? w2l : w2r;
    int idx = blockIdx.x * 256 + threadIdx.x;   // 0..16383 (grid.x = 64)
    int k = idx >> 7;
    int j = idx & 127;
    out[b * 16384 + idx] = src[j * D + k];
}

// ---------------------------------------------------------------------------
// Pass 1 of CSR build: histogram of dst.
__global__ __launch_bounds__(256) void hist_kernel(
    const int* __restrict__ dstI, int* __restrict__ degI, int E)
{
    int e = blockIdx.x * 256 + threadIdx.x;
    if (e < E) atomicAdd(&degI[dstI[e]], 1);
}

// Pass 2: single-block exclusive scan of degI -> rowptr (and cursor copy).
__global__ __launch_bounds__(1024) void scan_kernel(
    const int* __restrict__ degI, int* __restrict__ rowptr,
    int* __restrict__ cursor, int n)
{
    __shared__ int part[1024];
    const int t = threadIdx.x;
    const int chunk = (n + 1023) / 1024;
    const int beg = t * chunk;
    const int end = min(beg + chunk, n);
    int s = 0;
    for (int i = beg; i < end; ++i) s += degI[i];
    part[t] = s;
    __syncthreads();
    for (int off = 1; off < 1024; off <<= 1) {
        int v = (t >= off) ? part[t - off] : 0;
        __syncthreads();
        part[t] += v;
        __syncthreads();
    }
    int run = part[t] - s;                       // exclusive prefix
    for (int i = beg; i < end; ++i) {
        rowptr[i] = run; cursor[i] = run; run += degI[i];
    }
    if (t == 1023) rowptr[n] = part[1023];
}

// Pass 3: scatter src ids into dst-sorted order.
__global__ __launch_bounds__(256) void sort_kernel(
    const int* __restrict__ srcI, const int* __restrict__ dstI,
    int* __restrict__ cursor, int* __restrict__ sorted_src, int E)
{
    int e = blockIdx.x * 256 + threadIdx.x;
    if (e >= E) return;
    int pos = atomicAdd(&cursor[dstI[e]], 1);
    sorted_src[pos] = srcI[e];
}

// ---------------------------------------------------------------------------
// Gather-mean aggregation: one 64-lane wave per node, 2 cols (float2) / lane.
__global__ __launch_bounds__(256) void aggregate_kernel(
    const float* __restrict__ feat, const int* __restrict__ sorted_src,
    const int* __restrict__ rowptr, float* __restrict__ outbuf, int n)
{
    const int wid = (blockIdx.x * 256 + threadIdx.x) >> 6;   // node id
    if (wid >= n) return;
    const int lane = threadIdx.x & 63;
    const int beg = rowptr[wid];
    const int end = rowptr[wid + 1];

    float2 acc = make_float2(0.f, 0.f);
    int e = beg;
    for (; e + 3 < end; e += 4) {
        int s0 = sorted_src[e + 0];
        int s1 = sorted_src[e + 1];
        int s2 = sorted_src[e + 2];
        int s3 = sorted_src[e + 3];
        float2 v0 = *reinterpret_cast<const float2*>(feat + (size_t)s0 * D + lane * 2);
        float2 v1 = *reinterpret_cast<const float2*>(feat + (size_t)s1 * D + lane * 2);
        float2 v2 = *reinterpret_cast<const float2*>(feat + (size_t)s2 * D + lane * 2);
        float2 v3 = *reinterpret_cast<const float2*>(feat + (size_t)s3 * D + lane * 2);
        acc.x += v0.x + v1.x + v2.x + v3.x;
        acc.y += v0.y + v1.y + v2.y + v3.y;
    }
    for (; e < end; ++e) {
        int s0 = sorted_src[e];
        float2 v0 = *reinterpret_cast<const float2*>(feat + (size_t)s0 * D + lane * 2);
        acc.x += v0.x;
        acc.y += v0.y;
    }
    const float inv = (end > beg) ? 1.0f / (float)(end - beg) : 0.f;
    acc.x *= inv; acc.y *= inv;
    *reinterpret_cast<float2*>(outbuf + (size_t)wid * D + lane * 2) = acc;
}

// ---------------------------------------------------------------------------
// Fused SAGE layer: out[i][j] = relu( mean[i] @ WtL[:,j] + bL[j] + xin[i] @ WtR[:,j] )
// Block: 256 threads, 64 nodes x 128 cols. Thread: 4 rows x 8 cols.
// outbuf may alias meanbuf (rows staged to LDS before any write).
__global__ __launch_bounds__(256) void fused_gemm(
    const float* __restrict__ meanbuf,  // [n][128] mean neighbor feats
    const float* __restrict__ xin,      // [n][128] self feats
    const float* __restrict__ wtL,      // [128][128] (k-major)
    const float* __restrict__ wtR,      // [128][128] (k-major)
    const float* __restrict__ bL,       // [128]
    float* __restrict__ outbuf,         // [n][128]
    int n)
{
    __shared__ float aTile[64 * D];     // 32 KiB

    const int tid = threadIdx.x;
    const int node0 = blockIdx.x * 64;
    const int ng = tid & 15;            // col group: j0 = ng*8
    const int mg = tid >> 4;            // row group: rows mg*4 .. mg*4+3
    const int j0 = ng * 8;

    float acc[4][8];
#pragma unroll
    for (int m = 0; m < 4; ++m)
#pragma unroll
        for (int c = 0; c < 8; ++c) acc[m][c] = 0.0f;

    for (int p = 0; p < 2; ++p) {
        const float* A = p ? xin : meanbuf;
        const float* W = p ? wtR : wtL;

#pragma unroll
        for (int it = 0; it < 8; ++it) {
            int idx = tid + it * 256;          // 0..2047 float4 slots
            int r = idx >> 5;
            int c = idx & 31;
            int row = node0 + r;
            float4 v = make_float4(0.f, 0.f, 0.f, 0.f);
            if (row < n)
                v = *reinterpret_cast<const float4*>(A + (size_t)row * D + c * 4);
            *reinterpret_cast<float4*>(&aTile[r * D + c * 4]) = v;
        }
        __syncthreads();

        const float4* W4 = reinterpret_cast<const float4*>(W);
        const float4* aT4 = reinterpret_cast<const float4*>(aTile);

        for (int k4 = 0; k4 < 32; ++k4) {
            const float4 a0 = aT4[(mg * 4 + 0) * 32 + k4];
            const float4 a1 = aT4[(mg * 4 + 1) * 32 + k4];
            const float4 a2 = aT4[(mg * 4 + 2) * 32 + k4];
            const float4 a3 = aT4[(mg * 4 + 3) * 32 + k4];
#pragma unroll
            for (int kk = 0; kk < 4; ++kk) {
                const int k = k4 * 4 + kk;
                const float4 w0 = W4[k * 32 + ng * 2 + 0];
                const float4 w1 = W4[k * 32 + ng * 2 + 1];
                const float am0 = (kk == 0) ? a0.x : (kk == 1) ? a0.y : (kk == 2) ? a0.z : a0.w;
                const float am1 = (kk == 0) ? a1.x : (kk == 1) ? a1.y : (kk == 2) ? a1.z : a1.w;
                const float am2 = (kk == 0) ? a2.x : (kk == 1) ? a2.y : (kk == 2) ? a2.z : a2.w;
                const float am3 = (kk == 0) ? a3.x : (kk == 1) ? a3.y : (kk == 2) ? a3.z : a3.w;
                acc[0][0] += am0 * w0.x; acc[0][1] += am0 * w0.y;
                acc[0][2] += am0 * w0.z; acc[0][3] += am0 * w0.w;
                acc[0][4] += am0 * w1.x; acc[0][5] += am0 * w1.y;
                acc[0][6] += am0 * w1.z; acc[0][7] += am0 * w1.w;
                acc[1][0] += am1 * w0.x; acc[1][1] += am1 * w0.y;
                acc[1][2] += am1 * w0.z; acc[1][3] += am1 * w0.w;
                acc[1][4] += am1 * w1.x; acc[1][5] += am1 * w1.y;
                acc[1][6] += am1 * w1.z; acc[1][7] += am1 * w1.w;
                acc[2][0] += am2 * w0.x; acc[2][1] += am2 * w0.y;
                acc[2][2] += am2 * w0.z; acc[2][3] += am2 * w0.w;
                acc[2][4] += am2 * w1.x; acc[2][5] += am2 * w1.y;
                acc[2][6] += am2 * w1.z; acc[2][7] += am2 * w1.w;
                acc[3][0] += am3 * w0.x; acc[3][1] += am3 * w0.y;
                acc[3][2] += am3 * w0.z; acc[3][3] += am3 * w0.w;
                acc[3][4] += am3 * w1.x; acc[3][5] += am3 * w1.y;
                acc[3][6] += am3 * w1.z; acc[3][7] += am3 * w1.w;
            }
        }
        __syncthreads();
    }

    const float4 bl0 = *reinterpret_cast<const float4*>(bL + j0);
    const float4 bl1 = *reinterpret_cast<const float4*>(bL + j0 + 4);
#pragma unroll
    for (int m = 0; m < 4; ++m) {
        int row = node0 + mg * 4 + m;
        if (row < n) {
            float4 o0, o1;
            o0.x = fmaxf(acc[m][0] + bl0.x, 0.f);
            o0.y = fmaxf(acc[m][1] + bl0.y, 0.f);
            o0.z = fmaxf(acc[m][2] + bl0.z, 0.f);
            o0.w = fmaxf(acc[m][3] + bl0.w, 0.f);
            o1.x = fmaxf(acc[m][4] + bl1.x, 0.f);
            o1.y = fmaxf(acc[m][5] + bl1.y, 0.f);
            o1.z = fmaxf(acc[m][6] + bl1.z, 0.f);
            o1.w = fmaxf(acc[m][7] + bl1.w, 0.f);
            *reinterpret_cast<float4*>(outbuf + (size_t)row * D + j0) = o0;
            *reinterpret_cast<float4*>(outbuf + (size_t)row * D + j0 + 4) = o1;
        }
    }
}

// ---------------------------------------------------------------------------
// out[i][d] = sum_j h2[i][j] * w_out[d][j] + b_out[d]   (d_out = 4)
__global__ __launch_bounds__(256) void out_proj(
    const float* __restrict__ h2, const float* __restrict__ w_out,
    const float* __restrict__ b_out, float* __restrict__ out, int n)
{
    __shared__ float wsm[4 * D];
    wsm[threadIdx.x] = w_out[threadIdx.x];
    wsm[threadIdx.x + 256] = w_out[threadIdx.x + 256];
    __syncthreads();

    int t = blockIdx.x * 256 + threadIdx.x;
    int i = t >> 5;
    if (i >= n) return;
    int lane = t & 31;

    const float4 h = *reinterpret_cast<const float4*>(h2 + (size_t)i * D + lane * 4);
    float p[4];
#pragma unroll
    for (int d = 0; d < 4; ++d) {
        const float* wr = &wsm[d * D + lane * 4];
        p[d] = h.x * wr[0] + h.y * wr[1] + h.z * wr[2] + h.w * wr[3];
    }
#pragma unroll
    for (int off = 16; off > 0; off >>= 1) {
#pragma unroll
        for (int d = 0; d < 4; ++d) p[d] += __shfl_down(p[d], off, 32);
    }
    if (lane == 0) {
        const float4 b = *reinterpret_cast<const float4*>(b_out);
        float4 o;
        o.x = p[0] + b.x; o.y = p[1] + b.y; o.z = p[2] + b.z; o.w = p[3] + b.w;
        *reinterpret_cast<float4*>(out + (size_t)i * 4) = o;
    }
}

// ---------------------------------------------------------------------------
extern "C" void kernel_launch(void* const* d_in, const int* in_sizes, int n_in,
                              void* d_out, int out_size, void* d_ws, size_t ws_size,
                              hipStream_t stream)
{
    const float* x    = (const float*)d_in[0];
    const int*   ei   = (const int*)  d_in[1];
    const float* w1l  = (const float*)d_in[2];
    const float* b1l  = (const float*)d_in[3];
    const float* w1r  = (const float*)d_in[4];
    const float* w2l  = (const float*)d_in[5];
    const float* b2l  = (const float*)d_in[6];
    const float* w2r  = (const float*)d_in[7];
    const float* wout = (const float*)d_in[8];
    const float* bout = (const float*)d_in[9];

    const int n = in_sizes[0] / D;       // 100000
    const int E = in_sizes[1] / 2;       // 1600000
    const int* srcI = ei;
    const int* dstI = ei + E;

    char* ws = (char*)d_ws;
    int*   degI       = (int*)ws;                         ws += sizeof(int) * (size_t)n;        // reused as cursor
    int*   rowptr     = (int*)ws;                         ws += sizeof(int) * (size_t)(n + 1);
    int*   sorted_src = (int*)ws;                         ws += sizeof(int) * (size_t)E;
    float* bufA       = (float*)ws;                       ws += sizeof(float) * (size_t)n * D;
    float* bufB       = (float*)ws;                       ws += sizeof(float) * (size_t)n * D;
    float* wt         = (float*)ws;

    // ---- CSR build (once; reused by both layers) ----
    hipMemsetAsync(degI, 0, sizeof(int) * (size_t)n, stream);
    const int eblocks = (E + 255) / 256;
    hist_kernel<<<eblocks, 256, 0, stream>>>(dstI, degI, E);
    scan_kernel<<<1, 1024, 0, stream>>>(degI, rowptr, degI /*cursor*/, n);
    sort_kernel<<<eblocks, 256, 0, stream>>>(srcI, dstI, degI /*cursor*/, sorted_src, E);

    dim3 tgrid(64, 4);
    transpose_w<<<tgrid, 256, 0, stream>>>(w1l, w1r, w2l, w2r, wt);

    const int ablocks = (int)(((long long)n * 64 + 255) / 256);
    const int gblocks = (n + 63) / 64;

    // Layer 1
    aggregate_kernel<<<ablocks, 256, 0, stream>>>(x, sorted_src, rowptr, bufA, n);
    fused_gemm<<<gblocks, 256, 0, stream>>>(bufA, x, wt, wt + 16384, b1l, bufA, n);

    // Layer 2
    aggregate_kernel<<<ablocks, 256, 0, stream>>>(bufA, sorted_src, rowptr, bufB, n);
    fused_gemm<<<gblocks, 256, 0, stream>>>(bufB, bufA, wt + 2 * 16384, wt + 3 * 16384, b2l, bufB, n);

    // Output projection
    const int oblocks = (int)(((long long)n * 32 + 255) / 256);
    out_proj<<<oblocks, 256, 0, stream>>>(bufB, wout, bout, (float*)d_out, n);
}

// Round 3
// 793.347 us; speedup vs baseline: 7.2030x; 1.2546x over previous
//
#include <hip/hip_runtime.h>

constexpr int D = 128;

// ---------------------------------------------------------------------------
// Transpose the 4 weight matrices [j][k] -> [k][j] so GEMM B-loads stream.
__global__ __launch_bounds__(256) void transpose_w(
    const float* __restrict__ w1l, const float* __restrict__ w1r,
    const float* __restrict__ w2l, const float* __restrict__ w2r,
    float* __restrict__ out)
{
    int b = blockIdx.y;
    const float* src = (b == 0) ? w1l : (b == 1) ? w1r : (b == 2) ? w2l : w2r;
    int idx = blockIdx.x * 256 + threadIdx.x;   // 0..16383 (grid.x = 64)
    int k = idx >> 7;
    int j = idx & 127;
    out[b * 16384 + idx] = src[j * D + k];
}

// ---------------------------------------------------------------------------
// Pass 1 of CSR build: histogram of dst.
__global__ __launch_bounds__(256) void hist_kernel(
    const int* __restrict__ dstI, int* __restrict__ degI, int E)
{
    int e = blockIdx.x * 256 + threadIdx.x;
    if (e < E) atomicAdd(&degI[dstI[e]], 1);
}

// Pass 2a: per-block scan (256 elems/block). local = in-block exclusive prefix.
__global__ __launch_bounds__(256) void scan_blocks(
    const int* __restrict__ degI, int* __restrict__ local,
    int* __restrict__ blocksum, int n)
{
    __shared__ int tmp[256];
    const int t = threadIdx.x;
    const int i = blockIdx.x * 256 + t;
    const int v = (i < n) ? degI[i] : 0;
    tmp[t] = v;
    __syncthreads();
    for (int off = 1; off < 256; off <<= 1) {
        int u = (t >= off) ? tmp[t - off] : 0;
        __syncthreads();
        tmp[t] += u;
        __syncthreads();
    }
    if (i < n) local[i] = tmp[t] - v;
    if (t == 255) blocksum[blockIdx.x] = tmp[255];
}

// Pass 2b: single-block scan of block sums -> exclusive offsets (nb <= 1024).
__global__ __launch_bounds__(1024) void scan_sums(
    int* __restrict__ blocksum, int nb)
{
    __shared__ int tmp[1024];
    const int t = threadIdx.x;
    const int v = (t < nb) ? blocksum[t] : 0;
    tmp[t] = v;
    __syncthreads();
    for (int off = 1; off < 1024; off <<= 1) {
        int u = (t >= off) ? tmp[t - off] : 0;
        __syncthreads();
        tmp[t] += u;
        __syncthreads();
    }
    if (t < nb) blocksum[t] = tmp[t] - v;
}

// Pass 2c: rowptr[i] = local[i] + blockoffset; rowptr[n] = E; cursor copy.
__global__ __launch_bounds__(256) void finalize_scan(
    const int* __restrict__ local, const int* __restrict__ blocksum,
    int* __restrict__ rowptr, int* __restrict__ cursor, int n, int E)
{
    const int i = blockIdx.x * 256 + threadIdx.x;
    if (i < n) {
        int r = local[i] + blocksum[blockIdx.x];
        rowptr[i] = r;
        cursor[i] = r;
    } else if (i == n) {
        rowptr[n] = E;
    }
}

// Pass 3: scatter src ids into dst-sorted order.
__global__ __launch_bounds__(256) void sort_kernel(
    const int* __restrict__ srcI, const int* __restrict__ dstI,
    int* __restrict__ cursor, int* __restrict__ sorted_src, int E)
{
    int e = blockIdx.x * 256 + threadIdx.x;
    if (e >= E) return;
    int pos = atomicAdd(&cursor[dstI[e]], 1);
    sorted_src[pos] = srcI[e];
}

// ---------------------------------------------------------------------------
// Gather-mean aggregation: one 64-lane wave per node, 2 cols (float2) / lane.
__global__ __launch_bounds__(256) void aggregate_kernel(
    const float* __restrict__ feat, const int* __restrict__ sorted_src,
    const int* __restrict__ rowptr, float* __restrict__ outbuf, int n)
{
    const int wid = (blockIdx.x * 256 + threadIdx.x) >> 6;   // node id
    if (wid >= n) return;
    const int lane = threadIdx.x & 63;
    const int beg = rowptr[wid];
    const int end = rowptr[wid + 1];

    float2 acc = make_float2(0.f, 0.f);
    int e = beg;
    for (; e + 3 < end; e += 4) {
        int s0 = sorted_src[e + 0];
        int s1 = sorted_src[e + 1];
        int s2 = sorted_src[e + 2];
        int s3 = sorted_src[e + 3];
        float2 v0 = *reinterpret_cast<const float2*>(feat + (size_t)s0 * D + lane * 2);
        float2 v1 = *reinterpret_cast<const float2*>(feat + (size_t)s1 * D + lane * 2);
        float2 v2 = *reinterpret_cast<const float2*>(feat + (size_t)s2 * D + lane * 2);
        float2 v3 = *reinterpret_cast<const float2*>(feat + (size_t)s3 * D + lane * 2);
        acc.x += v0.x + v1.x + v2.x + v3.x;
        acc.y += v0.y + v1.y + v2.y + v3.y;
    }
    for (; e < end; ++e) {
        int s0 = sorted_src[e];
        float2 v0 = *reinterpret_cast<const float2*>(feat + (size_t)s0 * D + lane * 2);
        acc.x += v0.x;
        acc.y += v0.y;
    }
    const float inv = (end > beg) ? 1.0f / (float)(end - beg) : 0.f;
    acc.x *= inv; acc.y *= inv;
    *reinterpret_cast<float2*>(outbuf + (size_t)wid * D + lane * 2) = acc;
}

// ---------------------------------------------------------------------------
// Fused SAGE layer: out[i][j] = relu( mean[i] @ WtL[:,j] + bL[j] + xin[i] @ WtR[:,j] )
// Block: 256 threads, 64 nodes x 128 cols. Thread: 4 rows x 8 cols.
// outbuf may alias meanbuf (rows staged to LDS before any write).
__global__ __launch_bounds__(256) void fused_gemm(
    const float* __restrict__ meanbuf,  // [n][128] mean neighbor feats
    const float* __restrict__ xin,      // [n][128] self feats
    const float* __restrict__ wtL,      // [128][128] (k-major)
    const float* __restrict__ wtR,      // [128][128] (k-major)
    const float* __restrict__ bL,       // [128]
    float* __restrict__ outbuf,         // [n][128]
    int n)
{
    __shared__ float aTile[64 * D];     // 32 KiB

    const int tid = threadIdx.x;
    const int node0 = blockIdx.x * 64;
    const int ng = tid & 15;            // col group: j0 = ng*8
    const int mg = tid >> 4;            // row group: rows mg*4 .. mg*4+3
    const int j0 = ng * 8;

    float acc[4][8];
#pragma unroll
    for (int m = 0; m < 4; ++m)
#pragma unroll
        for (int c = 0; c < 8; ++c) acc[m][c] = 0.0f;

    for (int p = 0; p < 2; ++p) {
        const float* A = p ? xin : meanbuf;
        const float* W = p ? wtR : wtL;

#pragma unroll
        for (int it = 0; it < 8; ++it) {
            int idx = tid + it * 256;          // 0..2047 float4 slots
            int r = idx >> 5;
            int c = idx & 31;
            int row = node0 + r;
            float4 v = make_float4(0.f, 0.f, 0.f, 0.f);
            if (row < n)
                v = *reinterpret_cast<const float4*>(A + (size_t)row * D + c * 4);
            *reinterpret_cast<float4*>(&aTile[r * D + c * 4]) = v;
        }
        __syncthreads();

        const float4* W4 = reinterpret_cast<const float4*>(W);
        const float4* aT4 = reinterpret_cast<const float4*>(aTile);

        for (int k4 = 0; k4 < 32; ++k4) {
            const float4 a0 = aT4[(mg * 4 + 0) * 32 + k4];
            const float4 a1 = aT4[(mg * 4 + 1) * 32 + k4];
            const float4 a2 = aT4[(mg * 4 + 2) * 32 + k4];
            const float4 a3 = aT4[(mg * 4 + 3) * 32 + k4];
#pragma unroll
            for (int kk = 0; kk < 4; ++kk) {
                const int k = k4 * 4 + kk;
                const float4 w0 = W4[k * 32 + ng * 2 + 0];
                const float4 w1 = W4[k * 32 + ng * 2 + 1];
                const float am0 = (kk == 0) ? a0.x : (kk == 1) ? a0.y : (kk == 2) ? a0.z : a0.w;
                const float am1 = (kk == 0) ? a1.x : (kk == 1) ? a1.y : (kk == 2) ? a1.z : a1.w;
                const float am2 = (kk == 0) ? a2.x : (kk == 1) ? a2.y : (kk == 2) ? a2.z : a2.w;
                const float am3 = (kk == 0) ? a3.x : (kk == 1) ? a3.y : (kk == 2) ? a3.z : a3.w;
                acc[0][0] += am0 * w0.x; acc[0][1] += am0 * w0.y;
                acc[0][2] += am0 * w0.z; acc[0][3] += am0 * w0.w;
                acc[0][4] += am0 * w1.x; acc[0][5] += am0 * w1.y;
                acc[0][6] += am0 * w1.z; acc[0][7] += am0 * w1.w;
                acc[1][0] += am1 * w0.x; acc[1][1] += am1 * w0.y;
                acc[1][2] += am1 * w0.z; acc[1][3] += am1 * w0.w;
                acc[1][4] += am1 * w1.x; acc[1][5] += am1 * w1.y;
                acc[1][6] += am1 * w1.z; acc[1][7] += am1 * w1.w;
                acc[2][0] += am2 * w0.x; acc[2][1] += am2 * w0.y;
                acc[2][2] += am2 * w0.z; acc[2][3] += am2 * w0.w;
                acc[2][4] += am2 * w1.x; acc[2][5] += am2 * w1.y;
                acc[2][6] += am2 * w1.z; acc[2][7] += am2 * w1.w;
                acc[3][0] += am3 * w0.x; acc[3][1] += am3 * w0.y;
                acc[3][2] += am3 * w0.z; acc[3][3] += am3 * w0.w;
                acc[3][4] += am3 * w1.x; acc[3][5] += am3 * w1.y;
                acc[3][6] += am3 * w1.z; acc[3][7] += am3 * w1.w;
            }
        }
        __syncthreads();
    }

    const float4 bl0 = *reinterpret_cast<const float4*>(bL + j0);
    const float4 bl1 = *reinterpret_cast<const float4*>(bL + j0 + 4);
#pragma unroll
    for (int m = 0; m < 4; ++m) {
        int row = node0 + mg * 4 + m;
        if (row < n) {
            float4 o0, o1;
            o0.x = fmaxf(acc[m][0] + bl0.x, 0.f);
            o0.y = fmaxf(acc[m][1] + bl0.y, 0.f);
            o0.z = fmaxf(acc[m][2] + bl0.z, 0.f);
            o0.w = fmaxf(acc[m][3] + bl0.w, 0.f);
            o1.x = fmaxf(acc[m][4] + bl1.x, 0.f);
            o1.y = fmaxf(acc[m][5] + bl1.y, 0.f);
            o1.z = fmaxf(acc[m][6] + bl1.z, 0.f);
            o1.w = fmaxf(acc[m][7] + bl1.w, 0.f);
            *reinterpret_cast<float4*>(outbuf + (size_t)row * D + j0) = o0;
            *reinterpret_cast<float4*>(outbuf + (size_t)row * D + j0 + 4) = o1;
        }
    }
}

// ---------------------------------------------------------------------------
// out[i][d] = sum_j h2[i][j] * w_out[d][j] + b_out[d]   (d_out = 4)
__global__ __launch_bounds__(256) void out_proj(
    const float* __restrict__ h2, const float* __restrict__ w_out,
    const float* __restrict__ b_out, float* __restrict__ out, int n)
{
    __shared__ float wsm[4 * D];
    wsm[threadIdx.x] = w_out[threadIdx.x];
    wsm[threadIdx.x + 256] = w_out[threadIdx.x + 256];
    __syncthreads();

    int t = blockIdx.x * 256 + threadIdx.x;
    int i = t >> 5;
    if (i >= n) return;
    int lane = t & 31;

    const float4 h = *reinterpret_cast<const float4*>(h2 + (size_t)i * D + lane * 4);
    float p[4];
#pragma unroll
    for (int d = 0; d < 4; ++d) {
        const float* wr = &wsm[d * D + lane * 4];
        p[d] = h.x * wr[0] + h.y * wr[1] + h.z * wr[2] + h.w * wr[3];
    }
#pragma unroll
    for (int off = 16; off > 0; off >>= 1) {
#pragma unroll
        for (int d = 0; d < 4; ++d) p[d] += __shfl_down(p[d], off, 32);
    }
    if (lane == 0) {
        const float4 b = *reinterpret_cast<const float4*>(b_out);
        float4 o;
        o.x = p[0] + b.x; o.y = p[1] + b.y; o.z = p[2] + b.z; o.w = p[3] + b.w;
        *reinterpret_cast<float4*>(out + (size_t)i * 4) = o;
    }
}

// ---------------------------------------------------------------------------
extern "C" void kernel_launch(void* const* d_in, const int* in_sizes, int n_in,
                              void* d_out, int out_size, void* d_ws, size_t ws_size,
                              hipStream_t stream)
{
    const float* x    = (const float*)d_in[0];
    const int*   ei   = (const int*)  d_in[1];
    const float* w1l  = (const float*)d_in[2];
    const float* b1l  = (const float*)d_in[3];
    const float* w1r  = (const float*)d_in[4];
    const float* w2l  = (const float*)d_in[5];
    const float* b2l  = (const float*)d_in[6];
    const float* w2r  = (const float*)d_in[7];
    const float* wout = (const float*)d_in[8];
    const float* bout = (const float*)d_in[9];

    const int n = in_sizes[0] / D;       // 100000
    const int E = in_sizes[1] / 2;       // 1600000
    const int* srcI = ei;
    const int* dstI = ei + E;

    char* ws = (char*)d_ws;
    int*   degI       = (int*)ws;                         ws += sizeof(int) * (size_t)n;        // reused as cursor
    int*   rowptr     = (int*)ws;                         ws += sizeof(int) * (size_t)(n + 1);
    int*   sorted_src = (int*)ws;                         ws += sizeof(int) * (size_t)E;
    int*   local      = (int*)ws;                         ws += sizeof(int) * (size_t)n;
    int*   blocksum   = (int*)ws;                         ws += sizeof(int) * 1024;
    float* bufA       = (float*)ws;                       ws += sizeof(float) * (size_t)n * D;
    float* bufB       = (float*)ws;                       ws += sizeof(float) * (size_t)n * D;
    float* wt         = (float*)ws;

    // ---- CSR build (once; reused by both layers) ----
    hipMemsetAsync(degI, 0, sizeof(int) * (size_t)n, stream);
    const int eblocks = (E + 255) / 256;
    const int nblocks = (n + 255) / 256;          // 391 (must be <= 1024)
    hist_kernel<<<eblocks, 256, 0, stream>>>(dstI, degI, E);
    scan_blocks<<<nblocks, 256, 0, stream>>>(degI, local, blocksum, n);
    scan_sums<<<1, 1024, 0, stream>>>(blocksum, nblocks);
    finalize_scan<<<(n + 256) / 256, 256, 0, stream>>>(local, blocksum, rowptr,
                                                       degI /*cursor*/, n, E);
    sort_kernel<<<eblocks, 256, 0, stream>>>(srcI, dstI, degI /*cursor*/, sorted_src, E);

    dim3 tgrid(64, 4);
    transpose_w<<<tgrid, 256, 0, stream>>>(w1l, w1r, w2l, w2r, wt);

    const int ablocks = (int)(((long long)n * 64 + 255) / 256);
    const int gblocks = (n + 63) / 64;

    // Layer 1
    aggregate_kernel<<<ablocks, 256, 0, stream>>>(x, sorted_src, rowptr, bufA, n);
    fused_gemm<<<gblocks, 256, 0, stream>>>(bufA, x, wt, wt + 16384, b1l, bufA, n);

    // Layer 2
    aggregate_kernel<<<ablocks, 256, 0, stream>>>(bufA, sorted_src, rowptr, bufB, n);
    fused_gemm<<<gblocks, 256, 0, stream>>>(bufB, bufA, wt + 2 * 16384, wt + 3 * 16384, b2l, bufB, n);

    // Output projection
    const int oblocks = (int)(((long long)n * 32 + 255) / 256);
    out_proj<<<oblocks, 256, 0, stream>>>(bufB, wout, bout, (float*)d_out, n);
}

// Round 5
// 521.746 us; speedup vs baseline: 10.9526x; 1.5206x over previous
//
#include <hip/hip_runtime.h>

constexpr int D = 128;
using short8 = __attribute__((ext_vector_type(8))) short;
using f32x4  = __attribute__((ext_vector_type(4))) float;

__device__ __forceinline__ unsigned rneb(float f) {
    unsigned u = __float_as_uint(f);
    return (u + 0x7fffu + ((u >> 16) & 1u)) >> 16;   // bf16 bits (RNE)
}
__device__ __forceinline__ float lo2f(unsigned u) { return __uint_as_float(u << 16); }
__device__ __forceinline__ float hi2f(unsigned u) { return __uint_as_float(u & 0xffff0000u); }

// ---------------------------------------------------------------------------
// x (f32) -> bf16 bits, 4 elements/thread.
__global__ __launch_bounds__(256) void f32_to_bf16(
    const float* __restrict__ in, unsigned short* __restrict__ out, int n4)
{
    int i = blockIdx.x * 256 + threadIdx.x;
    if (i >= n4) return;
    float4 v = reinterpret_cast<const float4*>(in)[i];
    uint2 o;
    o.x = rneb(v.x) | (rneb(v.y) << 16);
    o.y = rneb(v.z) | (rneb(v.w) << 16);
    reinterpret_cast<uint2*>(out)[i] = o;
}

// ---------------------------------------------------------------------------
// Pack the 4 weight matrices [j][k] f32 into bf16 MFMA B-fragments:
// wf[m][f=c*4+ks][lane][i] = W_m[c*16 + (lane&15)][ks*32 + (lane>>4)*8 + i]
__global__ __launch_bounds__(256) void pack_w(
    const float* __restrict__ w1l, const float* __restrict__ w1r,
    const float* __restrict__ w2l, const float* __restrict__ w2r,
    unsigned short* __restrict__ wf)
{
    int t = blockIdx.x * 256 + threadIdx.x;          // 8192 threads
    int m = t >> 11;
    int r = t & 2047;                                 // f*64 + lane
    int f = r >> 6, lane = r & 63;
    int c = f >> 2, ks = f & 3;
    int col = c * 16 + (lane & 15);
    int k0 = ks * 32 + (lane >> 4) * 8;
    const float* W = (m == 0) ? w1l : (m == 1) ? w1r : (m == 2) ? w2l : w2r;
    unsigned short o[8];
#pragma unroll
    for (int i = 0; i < 8; ++i) o[i] = (unsigned short)rneb(W[col * D + k0 + i]);
    uint4 pk;
    pk.x = o[0] | ((unsigned)o[1] << 16);
    pk.y = o[2] | ((unsigned)o[3] << 16);
    pk.z = o[4] | ((unsigned)o[5] << 16);
    pk.w = o[6] | ((unsigned)o[7] << 16);
    reinterpret_cast<uint4*>(wf)[t] = pk;
}

// ---------------------------------------------------------------------------
// CSR build
__global__ __launch_bounds__(256) void hist_kernel(
    const int* __restrict__ dstI, int* __restrict__ degI, int E)
{
    int e = blockIdx.x * 256 + threadIdx.x;
    if (e < E) atomicAdd(&degI[dstI[e]], 1);
}

__global__ __launch_bounds__(256) void scan_blocks(
    const int* __restrict__ degI, int* __restrict__ local,
    int* __restrict__ blocksum, int n)
{
    __shared__ int tmp[256];
    const int t = threadIdx.x;
    const int i = blockIdx.x * 256 + t;
    const int v = (i < n) ? degI[i] : 0;
    tmp[t] = v;
    __syncthreads();
    for (int off = 1; off < 256; off <<= 1) {
        int u = (t >= off) ? tmp[t - off] : 0;
        __syncthreads();
        tmp[t] += u;
        __syncthreads();
    }
    if (i < n) local[i] = tmp[t] - v;
    if (t == 255) blocksum[blockIdx.x] = tmp[255];
}

__global__ __launch_bounds__(1024) void scan_sums(
    int* __restrict__ blocksum, int nb)
{
    __shared__ int tmp[1024];
    const int t = threadIdx.x;
    const int v = (t < nb) ? blocksum[t] : 0;
    tmp[t] = v;
    __syncthreads();
    for (int off = 1; off < 1024; off <<= 1) {
        int u = (t >= off) ? tmp[t - off] : 0;
        __syncthreads();
        tmp[t] += u;
        __syncthreads();
    }
    if (t < nb) blocksum[t] = tmp[t] - v;
}

__global__ __launch_bounds__(256) void finalize_scan(
    const int* __restrict__ local, const int* __restrict__ blocksum,
    int* __restrict__ rowptr, int* __restrict__ cursor, int n, int E)
{
    const int i = blockIdx.x * 256 + threadIdx.x;
    if (i < n) {
        int r = local[i] + blocksum[blockIdx.x];
        rowptr[i] = r;
        cursor[i] = r;
    } else if (i == n) {
        rowptr[n] = E;
    }
}

__global__ __launch_bounds__(256) void sort_kernel(
    const int* __restrict__ srcI, const int* __restrict__ dstI,
    int* __restrict__ cursor, int* __restrict__ sorted_src, int E)
{
    int e = blockIdx.x * 256 + threadIdx.x;
    if (e >= E) return;
    int pos = atomicAdd(&cursor[dstI[e]], 1);
    sorted_src[pos] = srcI[e];
}

// ---------------------------------------------------------------------------
// Gather-mean aggregation over bf16 features: one 64-lane wave per node,
// each lane owns 2 columns (one 4-byte load/row). fp32 accumulate, bf16 out.
__global__ __launch_bounds__(256) void aggregate_bf16(
    const unsigned short* __restrict__ feat, const int* __restrict__ sorted_src,
    const int* __restrict__ rowptr, unsigned short* __restrict__ outb, int n)
{
    const int wid = (blockIdx.x * 256 + threadIdx.x) >> 6;
    if (wid >= n) return;
    const int lane = threadIdx.x & 63;
    const int beg = rowptr[wid];
    const int end = rowptr[wid + 1];

    float ax = 0.f, ay = 0.f;
    int e = beg;
    for (; e + 7 < end; e += 8) {
        unsigned v[8];
#pragma unroll
        for (int q = 0; q < 8; ++q) {
            int s = sorted_src[e + q];
            v[q] = *reinterpret_cast<const unsigned*>(feat + (size_t)s * D + lane * 2);
        }
#pragma unroll
        for (int q = 0; q < 8; ++q) { ax += lo2f(v[q]); ay += hi2f(v[q]); }
    }
    for (; e < end; ++e) {
        int s = sorted_src[e];
        unsigned v = *reinterpret_cast<const unsigned*>(feat + (size_t)s * D + lane * 2);
        ax += lo2f(v); ay += hi2f(v);
    }
    const float inv = (end > beg) ? 1.0f / (float)(end - beg) : 0.f;
    ax *= inv; ay *= inv;
    unsigned pk = rneb(ax) | (rneb(ay) << 16);
    *reinterpret_cast<unsigned*>(outb + (size_t)wid * D + lane * 2) = pk;
}

// ---------------------------------------------------------------------------
// Fused SAGE layer via bf16 MFMA (no LDS):
// out[i][j] = relu( mean[i]@WL^T + bL + self[i]@WR^T )  -> bf16
// 4 waves/block, 16 rows/wave, N=128 (8 col-frags), K=128 (4 k-steps).
// outb may alias aMean: each wave reads only its own 16 rows before writing.
__global__ __launch_bounds__(256) void mfma_gemm(
    const unsigned short* __restrict__ aMean, const unsigned short* __restrict__ aSelf,
    const unsigned short* __restrict__ wfL, const unsigned short* __restrict__ wfR,
    const float* __restrict__ bL, unsigned short* __restrict__ outb, int n)
{
    const int lane = threadIdx.x & 63;
    const int wave = threadIdx.x >> 6;
    const int lo = lane & 15, hi = lane >> 4;
    const int row0 = blockIdx.x * 64 + wave * 16;
    int arow = row0 + lo;
    if (arow > n - 1) arow = n - 1;       // clamp stays inside this block's rows
    const size_t abase = (size_t)arow * D;

    f32x4 acc[8];
#pragma unroll
    for (int c = 0; c < 8; ++c) acc[c] = (f32x4){0.f, 0.f, 0.f, 0.f};

#pragma unroll
    for (int p = 0; p < 2; ++p) {
        const unsigned short* A  = p ? aSelf : aMean;
        const unsigned short* WF = p ? wfR : wfL;
#pragma unroll
        for (int ks = 0; ks < 4; ++ks) {
            short8 af = *reinterpret_cast<const short8*>(A + abase + ks * 32 + hi * 8);
#pragma unroll
            for (int c = 0; c < 8; ++c) {
                short8 bf = *reinterpret_cast<const short8*>(
                    WF + ((((c << 2) | ks) * 64 + lane) << 3));
                acc[c] = __builtin_amdgcn_mfma_f32_16x16x32_bf16(af, bf, acc[c], 0, 0, 0);
            }
        }
    }

#pragma unroll
    for (int c = 0; c < 8; ++c) {
        const int col = (c << 4) | lo;
        const float bias = bL[col];
#pragma unroll
        for (int j = 0; j < 4; ++j) {
            const int row = row0 + (hi << 2) + j;
            if (row < n)
                outb[(size_t)row * D + col] =
                    (unsigned short)rneb(fmaxf(acc[c][j] + bias, 0.f));
        }
    }
}

// ---------------------------------------------------------------------------
// out[i][d] = sum_j h2[i][j] * w_out[d][j] + b_out[d]   (d_out = 4), h2 bf16.
__global__ __launch_bounds__(256) void out_proj(
    const unsigned short* __restrict__ h2, const float* __restrict__ w_out,
    const float* __restrict__ b_out, float* __restrict__ out, int n)
{
    __shared__ float wsm[4 * D];
    wsm[threadIdx.x] = w_out[threadIdx.x];
    wsm[threadIdx.x + 256] = w_out[threadIdx.x + 256];
    __syncthreads();

    int t = blockIdx.x * 256 + threadIdx.x;
    int i = t >> 5;
    if (i >= n) return;
    int lane = t & 31;

    uint2 u = *reinterpret_cast<const uint2*>(h2 + (size_t)i * D + lane * 4);
    float h0 = lo2f(u.x), h1 = hi2f(u.x), h2v = lo2f(u.y), h3 = hi2f(u.y);
    float p[4];
#pragma unroll
    for (int d = 0; d < 4; ++d) {
        const float* wr = &wsm[d * D + lane * 4];
        p[d] = h0 * wr[0] + h1 * wr[1] + h2v * wr[2] + h3 * wr[3];
    }
#pragma unroll
    for (int off = 16; off > 0; off >>= 1) {
#pragma unroll
        for (int d = 0; d < 4; ++d) p[d] += __shfl_down(p[d], off, 32);
    }
    if (lane == 0) {
        const float4 b = *reinterpret_cast<const float4*>(b_out);
        float4 o;
        o.x = p[0] + b.x; o.y = p[1] + b.y; o.z = p[2] + b.z; o.w = p[3] + b.w;
        *reinterpret_cast<float4*>(out + (size_t)i * 4) = o;
    }
}

// ---------------------------------------------------------------------------
extern "C" void kernel_launch(void* const* d_in, const int* in_sizes, int n_in,
                              void* d_out, int out_size, void* d_ws, size_t ws_size,
                              hipStream_t stream)
{
    const float* x    = (const float*)d_in[0];
    const int*   ei   = (const int*)  d_in[1];
    const float* w1l  = (const float*)d_in[2];
    const float* b1l  = (const float*)d_in[3];
    const float* w1r  = (const float*)d_in[4];
    const float* w2l  = (const float*)d_in[5];
    const float* b2l  = (const float*)d_in[6];
    const float* w2r  = (const float*)d_in[7];
    const float* wout = (const float*)d_in[8];
    const float* bout = (const float*)d_in[9];

    const int n = in_sizes[0] / D;       // 100000
    const int E = in_sizes[1] / 2;       // 1600000
    const int* srcI = ei;
    const int* dstI = ei + E;

    auto align256 = [](size_t v) { return (v + 255) & ~(size_t)255; };
    char* base = (char*)d_ws;
    size_t off = 0;
    int* degI = (int*)(base + off);            off = align256(off + sizeof(int) * (size_t)n);
    int* rowptr = (int*)(base + off);          off = align256(off + sizeof(int) * (size_t)(n + 1));
    int* local = (int*)(base + off);           off = align256(off + sizeof(int) * (size_t)n);
    int* blocksum = (int*)(base + off);        off = align256(off + sizeof(int) * 1024);
    int* sorted_src = (int*)(base + off);      off = align256(off + sizeof(int) * (size_t)E);
    unsigned short* xb = (unsigned short*)(base + off);
    off = align256(off + sizeof(short) * (size_t)n * D);
    unsigned short* bufA = (unsigned short*)(base + off);
    off = align256(off + sizeof(short) * (size_t)n * D);
    unsigned short* bufB = (unsigned short*)(base + off);
    off = align256(off + sizeof(short) * (size_t)n * D);
    unsigned short* wf = (unsigned short*)(base + off);

    // ---- CSR build (once; reused by both layers) ----
    hipMemsetAsync(degI, 0, sizeof(int) * (size_t)n, stream);
    const int eblocks = (E + 255) / 256;
    const int nblocks = (n + 255) / 256;
    hist_kernel<<<eblocks, 256, 0, stream>>>(dstI, degI, E);
    scan_blocks<<<nblocks, 256, 0, stream>>>(degI, local, blocksum, n);
    scan_sums<<<1, 1024, 0, stream>>>(blocksum, nblocks);
    finalize_scan<<<(n + 256) / 256, 256, 0, stream>>>(local, blocksum, rowptr,
                                                       degI /*cursor*/, n, E);
    sort_kernel<<<eblocks, 256, 0, stream>>>(srcI, dstI, degI /*cursor*/, sorted_src, E);

    // ---- Weight fragment packing + x conversion ----
    pack_w<<<32, 256, 0, stream>>>(w1l, w1r, w2l, w2r, wf);
    const int n4 = n * (D / 4);
    f32_to_bf16<<<(n4 + 255) / 256, 256, 0, stream>>>(x, xb, n4);

    const int ablocks = (int)(((long long)n * 64 + 255) / 256);
    const int gblocks = (n + 63) / 64;

    // Layer 1
    aggregate_bf16<<<ablocks, 256, 0, stream>>>(xb, sorted_src, rowptr, bufA, n);
    mfma_gemm<<<gblocks, 256, 0, stream>>>(bufA, xb, wf, wf + 16384, b1l, bufA, n);

    // Layer 2
    aggregate_bf16<<<ablocks, 256, 0, stream>>>(bufA, sorted_src, rowptr, bufB, n);
    mfma_gemm<<<gblocks, 256, 0, stream>>>(bufB, bufA, wf + 2 * 16384, wf + 3 * 16384, b2l, bufB, n);

    // Output projection
    const int oblocks = (int)(((long long)n * 32 + 255) / 256);
    out_proj<<<oblocks, 256, 0, stream>>>(bufB, wout, bout, (float*)d_out, n);
}

// Round 6
// 448.988 us; speedup vs baseline: 12.7274x; 1.1620x over previous
//
#include <hip/hip_runtime.h>

constexpr int D = 128;
constexpr int BSHIFT = 10;              // 1024 nodes per bucket
constexpr int BNODES = 1 << BSHIFT;
constexpr int NBUCK_MAX = 128;          // n=100000 -> 98 buckets
using short8 = __attribute__((ext_vector_type(8))) short;
using f32x4  = __attribute__((ext_vector_type(4))) float;

__device__ __forceinline__ unsigned rneb(float f) {
    unsigned u = __float_as_uint(f);
    return (u + 0x7fffu + ((u >> 16) & 1u)) >> 16;   // bf16 bits (RNE)
}
__device__ __forceinline__ float lo2f(unsigned u) { return __uint_as_float(u << 16); }
__device__ __forceinline__ float hi2f(unsigned u) { return __uint_as_float(u & 0xffff0000u); }

// ---------------------------------------------------------------------------
__global__ __launch_bounds__(256) void f32_to_bf16(
    const float* __restrict__ in, unsigned short* __restrict__ out, int n4)
{
    int i = blockIdx.x * 256 + threadIdx.x;
    if (i >= n4) return;
    float4 v = reinterpret_cast<const float4*>(in)[i];
    uint2 o;
    o.x = rneb(v.x) | (rneb(v.y) << 16);
    o.y = rneb(v.z) | (rneb(v.w) << 16);
    reinterpret_cast<uint2*>(out)[i] = o;
}

// ---------------------------------------------------------------------------
// Pack the 4 weight matrices [j][k] f32 into bf16 MFMA B-fragments:
// wf[m][f=c*4+ks][lane][i] = W_m[c*16 + (lane&15)][ks*32 + (lane>>4)*8 + i]
__global__ __launch_bounds__(256) void pack_w(
    const float* __restrict__ w1l, const float* __restrict__ w1r,
    const float* __restrict__ w2l, const float* __restrict__ w2r,
    unsigned short* __restrict__ wf)
{
    int t = blockIdx.x * 256 + threadIdx.x;          // 8192 threads
    int m = t >> 11;
    int r = t & 2047;                                 // f*64 + lane
    int f = r >> 6, lane = r & 63;
    int c = f >> 2, ks = f & 3;
    int col = c * 16 + (lane & 15);
    int k0 = ks * 32 + (lane >> 4) * 8;
    const float* W = (m == 0) ? w1l : (m == 1) ? w1r : (m == 2) ? w2l : w2r;
    unsigned short o[8];
#pragma unroll
    for (int i = 0; i < 8; ++i) o[i] = (unsigned short)rneb(W[col * D + k0 + i]);
    uint4 pk;
    pk.x = o[0] | ((unsigned)o[1] << 16);
    pk.y = o[2] | ((unsigned)o[3] << 16);
    pk.z = o[4] | ((unsigned)o[5] << 16);
    pk.w = o[6] | ((unsigned)o[7] << 16);
    reinterpret_cast<uint4*>(wf)[t] = pk;
}

// ---------------------------------------------------------------------------
// CSR build
__global__ __launch_bounds__(256) void hist_kernel(
    const int* __restrict__ dstI, int* __restrict__ degI, int E)
{
    int e = blockIdx.x * 256 + threadIdx.x;
    if (e < E) atomicAdd(&degI[dstI[e]], 1);
}

__global__ __launch_bounds__(256) void scan_blocks(
    const int* __restrict__ degI, int* __restrict__ local,
    int* __restrict__ blocksum, int n)
{
    __shared__ int tmp[256];
    const int t = threadIdx.x;
    const int i = blockIdx.x * 256 + t;
    const int v = (i < n) ? degI[i] : 0;
    tmp[t] = v;
    __syncthreads();
    for (int off = 1; off < 256; off <<= 1) {
        int u = (t >= off) ? tmp[t - off] : 0;
        __syncthreads();
        tmp[t] += u;
        __syncthreads();
    }
    if (i < n) local[i] = tmp[t] - v;
    if (t == 255) blocksum[blockIdx.x] = tmp[255];
}

__global__ __launch_bounds__(1024) void scan_sums(
    int* __restrict__ blocksum, int nb)
{
    __shared__ int tmp[1024];
    const int t = threadIdx.x;
    const int v = (t < nb) ? blocksum[t] : 0;
    tmp[t] = v;
    __syncthreads();
    for (int off = 1; off < 1024; off <<= 1) {
        int u = (t >= off) ? tmp[t - off] : 0;
        __syncthreads();
        tmp[t] += u;
        __syncthreads();
    }
    if (t < nb) blocksum[t] = tmp[t] - v;
}

// rowptr[i] = local[i] + blockoffset; rowptr[n] = E; seed bucket cursors.
__global__ __launch_bounds__(256) void finalize_scan(
    const int* __restrict__ local, const int* __restrict__ blocksum,
    int* __restrict__ rowptr, int* __restrict__ gcursor, int n, int E)
{
    const int i = blockIdx.x * 256 + threadIdx.x;
    if (i < n) {
        int r = local[i] + blocksum[blockIdx.x];
        rowptr[i] = r;
        if ((i & (BNODES - 1)) == 0) gcursor[i >> BSHIFT] = r;
    } else if (i == n) {
        rowptr[n] = E;
    }
}

// ---------------------------------------------------------------------------
// Bin pass: 4096 edges/block. Per-bucket contiguous runs via one global
// atomicAdd per (block,bucket). Packed word = src | (dst & 1023) << 17.
__global__ __launch_bounds__(256) void bin_kernel(
    const int* __restrict__ srcI, const int* __restrict__ dstI,
    int* __restrict__ gcursor, unsigned* __restrict__ binned, int E, int nb)
{
    __shared__ int lhist[NBUCK_MAX];
    __shared__ int lbase[NBUCK_MAX];
    __shared__ int lcnt[NBUCK_MAX];
    const int t = threadIdx.x;
    const int e0 = blockIdx.x * 4096;
    for (int i = t; i < nb; i += 256) { lhist[i] = 0; lcnt[i] = 0; }
    __syncthreads();

    int dcache[16], scache[16];
#pragma unroll
    for (int q = 0; q < 16; ++q) {
        int e = e0 + q * 256 + t;
        int d = (e < E) ? dstI[e] : -1;
        dcache[q] = d;
        scache[q] = (e < E) ? srcI[e] : 0;
        if (d >= 0) atomicAdd(&lhist[d >> BSHIFT], 1);
    }
    __syncthreads();
    for (int b = t; b < nb; b += 256)
        if (lhist[b] > 0) lbase[b] = atomicAdd(&gcursor[b], lhist[b]);
    __syncthreads();
#pragma unroll
    for (int q = 0; q < 16; ++q) {
        int d = dcache[q];
        if (d >= 0) {
            int b = d >> BSHIFT;
            int off = atomicAdd(&lcnt[b], 1);
            binned[lbase[b] + off] =
                (unsigned)scache[q] | ((unsigned)(d & (BNODES - 1)) << 17);
        }
    }
}

// Final within-bucket counting scatter: one block per bucket; positions from
// an LDS cursor seeded with the bucket's rowptr slice. Writes stay in the
// bucket's ~64 KB window (L2-local).
__global__ __launch_bounds__(256) void bucket_sort(
    const unsigned* __restrict__ binned, const int* __restrict__ rowptr,
    int* __restrict__ sorted_src, int n)
{
    __shared__ int cursor[BNODES];
    const int node0 = blockIdx.x << BSHIFT;
    const int node1 = min(n, node0 + BNODES);
    for (int i = threadIdx.x; i < node1 - node0; i += 256)
        cursor[i] = rowptr[node0 + i];
    __syncthreads();
    const int ebeg = rowptr[node0];
    const int eend = rowptr[node1];
    for (int e = ebeg + threadIdx.x; e < eend; e += 256) {
        unsigned w = binned[e];
        int pos = atomicAdd(&cursor[w >> 17], 1);
        sorted_src[pos] = (int)(w & 0x1FFFF);
    }
}

// ---------------------------------------------------------------------------
// Gather-mean aggregation over bf16 features: one 64-lane wave per node,
// each lane owns 2 columns (one 4-byte load/row). fp32 accumulate, bf16 out.
__global__ __launch_bounds__(256) void aggregate_bf16(
    const unsigned short* __restrict__ feat, const int* __restrict__ sorted_src,
    const int* __restrict__ rowptr, unsigned short* __restrict__ outb, int n)
{
    const int wid = (blockIdx.x * 256 + threadIdx.x) >> 6;
    if (wid >= n) return;
    const int lane = threadIdx.x & 63;
    const int beg = rowptr[wid];
    const int end = rowptr[wid + 1];

    float ax = 0.f, ay = 0.f;
    int e = beg;
    for (; e + 7 < end; e += 8) {
        unsigned v[8];
#pragma unroll
        for (int q = 0; q < 8; ++q) {
            int s = sorted_src[e + q];
            v[q] = *reinterpret_cast<const unsigned*>(feat + (size_t)s * D + lane * 2);
        }
#pragma unroll
        for (int q = 0; q < 8; ++q) { ax += lo2f(v[q]); ay += hi2f(v[q]); }
    }
    for (; e < end; ++e) {
        int s = sorted_src[e];
        unsigned v = *reinterpret_cast<const unsigned*>(feat + (size_t)s * D + lane * 2);
        ax += lo2f(v); ay += hi2f(v);
    }
    const float inv = (end > beg) ? 1.0f / (float)(end - beg) : 0.f;
    ax *= inv; ay *= inv;
    unsigned pk = rneb(ax) | (rneb(ay) << 16);
    *reinterpret_cast<unsigned*>(outb + (size_t)wid * D + lane * 2) = pk;
}

// ---------------------------------------------------------------------------
// Fused SAGE layer via bf16 MFMA (no LDS):
// out[i][j] = relu( mean[i]@WL^T + bL + self[i]@WR^T )  -> bf16
// 4 waves/block, 16 rows/wave, N=128 (8 col-frags), K=128 (4 k-steps).
// outb may alias aMean: each wave reads only its own 16 rows before writing.
__global__ __launch_bounds__(256) void mfma_gemm(
    const unsigned short* __restrict__ aMean, const unsigned short* __restrict__ aSelf,
    const unsigned short* __restrict__ wfL, const unsigned short* __restrict__ wfR,
    const float* __restrict__ bL, unsigned short* __restrict__ outb, int n)
{
    const int lane = threadIdx.x & 63;
    const int wave = threadIdx.x >> 6;
    const int lo = lane & 15, hi = lane >> 4;
    const int row0 = blockIdx.x * 64 + wave * 16;
    int arow = row0 + lo;
    if (arow > n - 1) arow = n - 1;       // clamp stays inside this block's rows
    const size_t abase = (size_t)arow * D;

    f32x4 acc[8];
#pragma unroll
    for (int c = 0; c < 8; ++c) acc[c] = (f32x4){0.f, 0.f, 0.f, 0.f};

#pragma unroll
    for (int p = 0; p < 2; ++p) {
        const unsigned short* A  = p ? aSelf : aMean;
        const unsigned short* WF = p ? wfR : wfL;
#pragma unroll
        for (int ks = 0; ks < 4; ++ks) {
            short8 af = *reinterpret_cast<const short8*>(A + abase + ks * 32 + hi * 8);
#pragma unroll
            for (int c = 0; c < 8; ++c) {
                short8 bf = *reinterpret_cast<const short8*>(
                    WF + ((((c << 2) | ks) * 64 + lane) << 3));
                acc[c] = __builtin_amdgcn_mfma_f32_16x16x32_bf16(af, bf, acc[c], 0, 0, 0);
            }
        }
    }

#pragma unroll
    for (int c = 0; c < 8; ++c) {
        const int col = (c << 4) | lo;
        const float bias = bL[col];
#pragma unroll
        for (int j = 0; j < 4; ++j) {
            const int row = row0 + (hi << 2) + j;
            if (row < n)
                outb[(size_t)row * D + col] =
                    (unsigned short)rneb(fmaxf(acc[c][j] + bias, 0.f));
        }
    }
}

// ---------------------------------------------------------------------------
// out[i][d] = sum_j h2[i][j] * w_out[d][j] + b_out[d]   (d_out = 4), h2 bf16.
__global__ __launch_bounds__(256) void out_proj(
    const unsigned short* __restrict__ h2, const float* __restrict__ w_out,
    const float* __restrict__ b_out, float* __restrict__ out, int n)
{
    __shared__ float wsm[4 * D];
    wsm[threadIdx.x] = w_out[threadIdx.x];
    wsm[threadIdx.x + 256] = w_out[threadIdx.x + 256];
    __syncthreads();

    int t = blockIdx.x * 256 + threadIdx.x;
    int i = t >> 5;
    if (i >= n) return;
    int lane = t & 31;

    uint2 u = *reinterpret_cast<const uint2*>(h2 + (size_t)i * D + lane * 4);
    float h0 = lo2f(u.x), h1 = hi2f(u.x), h2v = lo2f(u.y), h3 = hi2f(u.y);
    float p[4];
#pragma unroll
    for (int d = 0; d < 4; ++d) {
        const float* wr = &wsm[d * D + lane * 4];
        p[d] = h0 * wr[0] + h1 * wr[1] + h2v * wr[2] + h3 * wr[3];
    }
#pragma unroll
    for (int off = 16; off > 0; off >>= 1) {
#pragma unroll
        for (int d = 0; d < 4; ++d) p[d] += __shfl_down(p[d], off, 32);
    }
    if (lane == 0) {
        const float4 b = *reinterpret_cast<const float4*>(b_out);
        float4 o;
        o.x = p[0] + b.x; o.y = p[1] + b.y; o.z = p[2] + b.z; o.w = p[3] + b.w;
        *reinterpret_cast<float4*>(out + (size_t)i * 4) = o;
    }
}

// ---------------------------------------------------------------------------
extern "C" void kernel_launch(void* const* d_in, const int* in_sizes, int n_in,
                              void* d_out, int out_size, void* d_ws, size_t ws_size,
                              hipStream_t stream)
{
    const float* x    = (const float*)d_in[0];
    const int*   ei   = (const int*)  d_in[1];
    const float* w1l  = (const float*)d_in[2];
    const float* b1l  = (const float*)d_in[3];
    const float* w1r  = (const float*)d_in[4];
    const float* w2l  = (const float*)d_in[5];
    const float* b2l  = (const float*)d_in[6];
    const float* w2r  = (const float*)d_in[7];
    const float* wout = (const float*)d_in[8];
    const float* bout = (const float*)d_in[9];

    const int n = in_sizes[0] / D;       // 100000
    const int E = in_sizes[1] / 2;       // 1600000
    const int* srcI = ei;
    const int* dstI = ei + E;
    const int nbuck = (n + BNODES - 1) >> BSHIFT;   // 98

    auto align256 = [](size_t v) { return (v + 255) & ~(size_t)255; };
    char* base = (char*)d_ws;
    size_t off = 0;
    int* degI = (int*)(base + off);            off = align256(off + sizeof(int) * (size_t)n);
    int* rowptr = (int*)(base + off);          off = align256(off + sizeof(int) * (size_t)(n + 1));
    int* local = (int*)(base + off);           off = align256(off + sizeof(int) * (size_t)n);
    int* blocksum = (int*)(base + off);        off = align256(off + sizeof(int) * 1024);
    int* gcursor = (int*)(base + off);         off = align256(off + sizeof(int) * NBUCK_MAX);
    int* sorted_src = (int*)(base + off);      off = align256(off + sizeof(int) * (size_t)E);
    unsigned* binned = (unsigned*)(base + off); off = align256(off + sizeof(unsigned) * (size_t)E);
    unsigned short* xb = (unsigned short*)(base + off);
    off = align256(off + sizeof(short) * (size_t)n * D);
    unsigned short* bufA = (unsigned short*)(base + off);
    off = align256(off + sizeof(short) * (size_t)n * D);
    unsigned short* bufB = (unsigned short*)(base + off);
    off = align256(off + sizeof(short) * (size_t)n * D);
    unsigned short* wf = (unsigned short*)(base + off);

    // ---- CSR build (once; reused by both layers) ----
    hipMemsetAsync(degI, 0, sizeof(int) * (size_t)n, stream);
    const int eblocks = (E + 255) / 256;
    const int nblocks = (n + 255) / 256;
    hist_kernel<<<eblocks, 256, 0, stream>>>(dstI, degI, E);
    scan_blocks<<<nblocks, 256, 0, stream>>>(degI, local, blocksum, n);
    scan_sums<<<1, 1024, 0, stream>>>(blocksum, nblocks);
    finalize_scan<<<(n + 256) / 256, 256, 0, stream>>>(local, blocksum, rowptr,
                                                       gcursor, n, E);
    bin_kernel<<<(E + 4095) / 4096, 256, 0, stream>>>(srcI, dstI, gcursor,
                                                      binned, E, nbuck);
    bucket_sort<<<nbuck, 256, 0, stream>>>(binned, rowptr, sorted_src, n);

    // ---- Weight fragment packing + x conversion ----
    pack_w<<<32, 256, 0, stream>>>(w1l, w1r, w2l, w2r, wf);
    const int n4 = n * (D / 4);
    f32_to_bf16<<<(n4 + 255) / 256, 256, 0, stream>>>(x, xb, n4);

    const int ablocks = (int)(((long long)n * 64 + 255) / 256);
    const int gblocks = (n + 63) / 64;

    // Layer 1
    aggregate_bf16<<<ablocks, 256, 0, stream>>>(xb, sorted_src, rowptr, bufA, n);
    mfma_gemm<<<gblocks, 256, 0, stream>>>(bufA, xb, wf, wf + 16384, b1l, bufA, n);

    // Layer 2
    aggregate_bf16<<<ablocks, 256, 0, stream>>>(bufA, sorted_src, rowptr, bufB, n);
    mfma_gemm<<<gblocks, 256, 0, stream>>>(bufB, bufA, wf + 2 * 16384, wf + 3 * 16384, b2l, bufB, n);

    // Output projection
    const int oblocks = (int)(((long long)n * 32 + 255) / 256);
    out_proj<<<oblocks, 256, 0, stream>>>(bufB, wout, bout, (float*)d_out, n);
}

// Round 7
// 425.285 us; speedup vs baseline: 13.4368x; 1.0557x over previous
//
#include <hip/hip_runtime.h>

constexpr int D = 128;
constexpr int BSHIFT = 10;              // 1024 nodes per bucket
constexpr int BNODES = 1 << BSHIFT;
constexpr int NBUCK_MAX = 128;          // n=100000 -> 98 buckets
using short8 = __attribute__((ext_vector_type(8))) short;
using f32x4  = __attribute__((ext_vector_type(4))) float;

__device__ __forceinline__ unsigned rneb(float f) {
    unsigned u = __float_as_uint(f);
    return (u + 0x7fffu + ((u >> 16) & 1u)) >> 16;   // bf16 bits (RNE)
}
__device__ __forceinline__ float lo2f(unsigned u) { return __uint_as_float(u << 16); }
__device__ __forceinline__ float hi2f(unsigned u) { return __uint_as_float(u & 0xffff0000u); }

// ---------------------------------------------------------------------------
__global__ __launch_bounds__(256) void f32_to_bf16(
    const float* __restrict__ in, unsigned short* __restrict__ out, int n4)
{
    int i = blockIdx.x * 256 + threadIdx.x;
    if (i >= n4) return;
    float4 v = reinterpret_cast<const float4*>(in)[i];
    uint2 o;
    o.x = rneb(v.x) | (rneb(v.y) << 16);
    o.y = rneb(v.z) | (rneb(v.w) << 16);
    reinterpret_cast<uint2*>(out)[i] = o;
}

// ---------------------------------------------------------------------------
// Pack the 4 weight matrices [j][k] f32 into bf16 MFMA B-fragments:
// wf[m][f=c*4+ks][lane][i] = W_m[c*16 + (lane&15)][ks*32 + (lane>>4)*8 + i]
__global__ __launch_bounds__(256) void pack_w(
    const float* __restrict__ w1l, const float* __restrict__ w1r,
    const float* __restrict__ w2l, const float* __restrict__ w2r,
    unsigned short* __restrict__ wf)
{
    int t = blockIdx.x * 256 + threadIdx.x;          // 8192 threads
    int m = t >> 11;
    int r = t & 2047;                                 // f*64 + lane
    int f = r >> 6, lane = r & 63;
    int c = f >> 2, ks = f & 3;
    int col = c * 16 + (lane & 15);
    int k0 = ks * 32 + (lane >> 4) * 8;
    const float* W = (m == 0) ? w1l : (m == 1) ? w1r : (m == 2) ? w2l : w2r;
    unsigned short o[8];
#pragma unroll
    for (int i = 0; i < 8; ++i) o[i] = (unsigned short)rneb(W[col * D + k0 + i]);
    uint4 pk;
    pk.x = o[0] | ((unsigned)o[1] << 16);
    pk.y = o[2] | ((unsigned)o[3] << 16);
    pk.z = o[4] | ((unsigned)o[5] << 16);
    pk.w = o[6] | ((unsigned)o[7] << 16);
    reinterpret_cast<uint4*>(wf)[t] = pk;
}

// ---------------------------------------------------------------------------
// CSR build
__global__ __launch_bounds__(256) void hist_kernel(
    const int* __restrict__ dstI, int* __restrict__ degI, int E)
{
    int e = blockIdx.x * 256 + threadIdx.x;
    if (e < E) atomicAdd(&degI[dstI[e]], 1);
}

__global__ __launch_bounds__(256) void scan_blocks(
    const int* __restrict__ degI, int* __restrict__ local,
    int* __restrict__ blocksum, int n)
{
    __shared__ int tmp[256];
    const int t = threadIdx.x;
    const int i = blockIdx.x * 256 + t;
    const int v = (i < n) ? degI[i] : 0;
    tmp[t] = v;
    __syncthreads();
    for (int off = 1; off < 256; off <<= 1) {
        int u = (t >= off) ? tmp[t - off] : 0;
        __syncthreads();
        tmp[t] += u;
        __syncthreads();
    }
    if (i < n) local[i] = tmp[t] - v;
    if (t == 255) blocksum[blockIdx.x] = tmp[255];
}

__global__ __launch_bounds__(1024) void scan_sums(
    int* __restrict__ blocksum, int nb)
{
    __shared__ int tmp[1024];
    const int t = threadIdx.x;
    const int v = (t < nb) ? blocksum[t] : 0;
    tmp[t] = v;
    __syncthreads();
    for (int off = 1; off < 1024; off <<= 1) {
        int u = (t >= off) ? tmp[t - off] : 0;
        __syncthreads();
        tmp[t] += u;
        __syncthreads();
    }
    if (t < nb) blocksum[t] = tmp[t] - v;
}

// rowptr[i] = local[i] + blockoffset; rowptr[n] = E; seed bucket cursors.
__global__ __launch_bounds__(256) void finalize_scan(
    const int* __restrict__ local, const int* __restrict__ blocksum,
    int* __restrict__ rowptr, int* __restrict__ gcursor, int n, int E)
{
    const int i = blockIdx.x * 256 + threadIdx.x;
    if (i < n) {
        int r = local[i] + blocksum[blockIdx.x];
        rowptr[i] = r;
        if ((i & (BNODES - 1)) == 0) gcursor[i >> BSHIFT] = r;
    } else if (i == n) {
        rowptr[n] = E;
    }
}

// ---------------------------------------------------------------------------
// Bin pass: 4096 edges/block. Per-bucket contiguous runs via one global
// atomicAdd per (block,bucket). Packed word = src | (dst & 1023) << 17.
__global__ __launch_bounds__(256) void bin_kernel(
    const int* __restrict__ srcI, const int* __restrict__ dstI,
    int* __restrict__ gcursor, unsigned* __restrict__ binned, int E, int nb)
{
    __shared__ int lhist[NBUCK_MAX];
    __shared__ int lbase[NBUCK_MAX];
    __shared__ int lcnt[NBUCK_MAX];
    const int t = threadIdx.x;
    const int e0 = blockIdx.x * 4096;
    for (int i = t; i < nb; i += 256) { lhist[i] = 0; lcnt[i] = 0; }
    __syncthreads();

    int dcache[16], scache[16];
#pragma unroll
    for (int q = 0; q < 16; ++q) {
        int e = e0 + q * 256 + t;
        int d = (e < E) ? dstI[e] : -1;
        dcache[q] = d;
        scache[q] = (e < E) ? srcI[e] : 0;
        if (d >= 0) atomicAdd(&lhist[d >> BSHIFT], 1);
    }
    __syncthreads();
    for (int b = t; b < nb; b += 256)
        if (lhist[b] > 0) lbase[b] = atomicAdd(&gcursor[b], lhist[b]);
    __syncthreads();
#pragma unroll
    for (int q = 0; q < 16; ++q) {
        int d = dcache[q];
        if (d >= 0) {
            int b = d >> BSHIFT;
            int off = atomicAdd(&lcnt[b], 1);
            binned[lbase[b] + off] =
                (unsigned)scache[q] | ((unsigned)(d & (BNODES - 1)) << 17);
        }
    }
}

// Final within-bucket counting scatter: one block per bucket; positions from
// an LDS cursor seeded with the bucket's rowptr slice.
__global__ __launch_bounds__(256) void bucket_sort(
    const unsigned* __restrict__ binned, const int* __restrict__ rowptr,
    int* __restrict__ sorted_src, int n)
{
    __shared__ int cursor[BNODES];
    const int node0 = blockIdx.x << BSHIFT;
    const int node1 = min(n, node0 + BNODES);
    for (int i = threadIdx.x; i < node1 - node0; i += 256)
        cursor[i] = rowptr[node0 + i];
    __syncthreads();
    const int ebeg = rowptr[node0];
    const int eend = rowptr[node1];
    for (int e = ebeg + threadIdx.x; e < eend; e += 256) {
        unsigned w = binned[e];
        int pos = atomicAdd(&cursor[w >> 17], 1);
        sorted_src[pos] = (int)(w & 0x1FFFF);
    }
}

// ---------------------------------------------------------------------------
// Gather-mean aggregation, wide-load version: one 64-lane wave per node.
// lane = (sub = lane>>4, part = lane&15); each lane loads dwordx4 (16 B =
// 8 bf16) of row src[e+sub] at column slice part*8. One wave VMEM instr
// covers 4 rows (1024 B). Cross-sub reduce via shfl_xor(16|32) at the end.
__global__ __launch_bounds__(256) void aggregate_bf16(
    const unsigned short* __restrict__ feat, const int* __restrict__ sorted_src,
    const int* __restrict__ rowptr, unsigned short* __restrict__ outb, int n)
{
    const int wid = (blockIdx.x * 256 + threadIdx.x) >> 6;
    if (wid >= n) return;
    const int lane = threadIdx.x & 63;
    const int sub = lane >> 4;
    const int part = lane & 15;
    const int beg = rowptr[wid];
    const int end = rowptr[wid + 1];
    const int deg = end - beg;

    float acc[8];
#pragma unroll
    for (int j = 0; j < 8; ++j) acc[j] = 0.f;

    int e = beg;
    // main loop: 8 edges per iteration (2 dwordx4 in flight per lane)
    for (; e + 8 <= end; e += 8) {
        const int s0 = sorted_src[e + sub];
        const int s1 = sorted_src[e + 4 + sub];
        const uint4 v0 = *reinterpret_cast<const uint4*>(feat + (size_t)s0 * D + part * 8);
        const uint4 v1 = *reinterpret_cast<const uint4*>(feat + (size_t)s1 * D + part * 8);
        acc[0] += lo2f(v0.x); acc[1] += hi2f(v0.x);
        acc[2] += lo2f(v0.y); acc[3] += hi2f(v0.y);
        acc[4] += lo2f(v0.z); acc[5] += hi2f(v0.z);
        acc[6] += lo2f(v0.w); acc[7] += hi2f(v0.w);
        acc[0] += lo2f(v1.x); acc[1] += hi2f(v1.x);
        acc[2] += lo2f(v1.y); acc[3] += hi2f(v1.y);
        acc[4] += lo2f(v1.z); acc[5] += hi2f(v1.z);
        acc[6] += lo2f(v1.w); acc[7] += hi2f(v1.w);
    }
    // one 4-edge chunk
    if (e + 4 <= end) {
        const int s0 = sorted_src[e + sub];
        const uint4 v0 = *reinterpret_cast<const uint4*>(feat + (size_t)s0 * D + part * 8);
        acc[0] += lo2f(v0.x); acc[1] += hi2f(v0.x);
        acc[2] += lo2f(v0.y); acc[3] += hi2f(v0.y);
        acc[4] += lo2f(v0.z); acc[5] += hi2f(v0.z);
        acc[6] += lo2f(v0.w); acc[7] += hi2f(v0.w);
        e += 4;
    }
    // tail (1-3 edges): predicate inactive subs with a 0 multiplier
    if (e < end) {
        const int ei = e + sub;
        const bool act = ei < end;
        const int s = act ? sorted_src[ei] : sorted_src[beg];
        const float m = act ? 1.f : 0.f;
        const uint4 v = *reinterpret_cast<const uint4*>(feat + (size_t)s * D + part * 8);
        acc[0] += m * lo2f(v.x); acc[1] += m * hi2f(v.x);
        acc[2] += m * lo2f(v.y); acc[3] += m * hi2f(v.y);
        acc[4] += m * lo2f(v.z); acc[5] += m * hi2f(v.z);
        acc[6] += m * lo2f(v.w); acc[7] += m * hi2f(v.w);
    }

    // reduce the 4 sub-groups (lanes 16/32 apart hold the same column slice)
#pragma unroll
    for (int j = 0; j < 8; ++j) {
        acc[j] += __shfl_xor(acc[j], 16);
        acc[j] += __shfl_xor(acc[j], 32);
    }

    if (sub == 0) {
        const float inv = (deg > 0) ? 1.0f / (float)deg : 0.f;
        uint4 pk;
        pk.x = rneb(acc[0] * inv) | (rneb(acc[1] * inv) << 16);
        pk.y = rneb(acc[2] * inv) | (rneb(acc[3] * inv) << 16);
        pk.z = rneb(acc[4] * inv) | (rneb(acc[5] * inv) << 16);
        pk.w = rneb(acc[6] * inv) | (rneb(acc[7] * inv) << 16);
        *reinterpret_cast<uint4*>(outb + (size_t)wid * D + part * 8) = pk;
    }
}

// ---------------------------------------------------------------------------
// Fused SAGE layer via bf16 MFMA (no LDS):
// out[i][j] = relu( mean[i]@WL^T + bL + self[i]@WR^T )  -> bf16
// 4 waves/block, 16 rows/wave, N=128 (8 col-frags), K=128 (4 k-steps).
// outb may alias aMean: each wave reads only its own 16 rows before writing.
__global__ __launch_bounds__(256) void mfma_gemm(
    const unsigned short* __restrict__ aMean, const unsigned short* __restrict__ aSelf,
    const unsigned short* __restrict__ wfL, const unsigned short* __restrict__ wfR,
    const float* __restrict__ bL, unsigned short* __restrict__ outb, int n)
{
    const int lane = threadIdx.x & 63;
    const int wave = threadIdx.x >> 6;
    const int lo = lane & 15, hi = lane >> 4;
    const int row0 = blockIdx.x * 64 + wave * 16;
    int arow = row0 + lo;
    if (arow > n - 1) arow = n - 1;       // clamp stays inside this block's rows
    const size_t abase = (size_t)arow * D;

    f32x4 acc[8];
#pragma unroll
    for (int c = 0; c < 8; ++c) acc[c] = (f32x4){0.f, 0.f, 0.f, 0.f};

#pragma unroll
    for (int p = 0; p < 2; ++p) {
        const unsigned short* A  = p ? aSelf : aMean;
        const unsigned short* WF = p ? wfR : wfL;
#pragma unroll
        for (int ks = 0; ks < 4; ++ks) {
            short8 af = *reinterpret_cast<const short8*>(A + abase + ks * 32 + hi * 8);
#pragma unroll
            for (int c = 0; c < 8; ++c) {
                short8 bf = *reinterpret_cast<const short8*>(
                    WF + ((((c << 2) | ks) * 64 + lane) << 3));
                acc[c] = __builtin_amdgcn_mfma_f32_16x16x32_bf16(af, bf, acc[c], 0, 0, 0);
            }
        }
    }

#pragma unroll
    for (int c = 0; c < 8; ++c) {
        const int col = (c << 4) | lo;
        const float bias = bL[col];
#pragma unroll
        for (int j = 0; j < 4; ++j) {
            const int row = row0 + (hi << 2) + j;
            if (row < n)
                outb[(size_t)row * D + col] =
                    (unsigned short)rneb(fmaxf(acc[c][j] + bias, 0.f));
        }
    }
}

// ---------------------------------------------------------------------------
// out[i][d] = sum_j h2[i][j] * w_out[d][j] + b_out[d]   (d_out = 4), h2 bf16.
__global__ __launch_bounds__(256) void out_proj(
    const unsigned short* __restrict__ h2, const float* __restrict__ w_out,
    const float* __restrict__ b_out, float* __restrict__ out, int n)
{
    __shared__ float wsm[4 * D];
    wsm[threadIdx.x] = w_out[threadIdx.x];
    wsm[threadIdx.x + 256] = w_out[threadIdx.x + 256];
    __syncthreads();

    int t = blockIdx.x * 256 + threadIdx.x;
    int i = t >> 5;
    if (i >= n) return;
    int lane = t & 31;

    uint2 u = *reinterpret_cast<const uint2*>(h2 + (size_t)i * D + lane * 4);
    float h0 = lo2f(u.x), h1 = hi2f(u.x), h2v = lo2f(u.y), h3 = hi2f(u.y);
    float p[4];
#pragma unroll
    for (int d = 0; d < 4; ++d) {
        const float* wr = &wsm[d * D + lane * 4];
        p[d] = h0 * wr[0] + h1 * wr[1] + h2v * wr[2] + h3 * wr[3];
    }
#pragma unroll
    for (int off = 16; off > 0; off >>= 1) {
#pragma unroll
        for (int d = 0; d < 4; ++d) p[d] += __shfl_down(p[d], off, 32);
    }
    if (lane == 0) {
        const float4 b = *reinterpret_cast<const float4*>(b_out);
        float4 o;
        o.x = p[0] + b.x; o.y = p[1] + b.y; o.z = p[2] + b.z; o.w = p[3] + b.w;
        *reinterpret_cast<float4*>(out + (size_t)i * 4) = o;
    }
}

// ---------------------------------------------------------------------------
extern "C" void kernel_launch(void* const* d_in, const int* in_sizes, int n_in,
                              void* d_out, int out_size, void* d_ws, size_t ws_size,
                              hipStream_t stream)
{
    const float* x    = (const float*)d_in[0];
    const int*   ei   = (const int*)  d_in[1];
    const float* w1l  = (const float*)d_in[2];
    const float* b1l  = (const float*)d_in[3];
    const float* w1r  = (const float*)d_in[4];
    const float* w2l  = (const float*)d_in[5];
    const float* b2l  = (const float*)d_in[6];
    const float* w2r  = (const float*)d_in[7];
    const float* wout = (const float*)d_in[8];
    const float* bout = (const float*)d_in[9];

    const int n = in_sizes[0] / D;       // 100000
    const int E = in_sizes[1] / 2;       // 1600000
    const int* srcI = ei;
    const int* dstI = ei + E;
    const int nbuck = (n + BNODES - 1) >> BSHIFT;   // 98

    auto align256 = [](size_t v) { return (v + 255) & ~(size_t)255; };
    char* base = (char*)d_ws;
    size_t off = 0;
    int* degI = (int*)(base + off);            off = align256(off + sizeof(int) * (size_t)n);
    int* rowptr = (int*)(base + off);          off = align256(off + sizeof(int) * (size_t)(n + 1));
    int* local = (int*)(base + off);           off = align256(off + sizeof(int) * (size_t)n);
    int* blocksum = (int*)(base + off);        off = align256(off + sizeof(int) * 1024);
    int* gcursor = (int*)(base + off);         off = align256(off + sizeof(int) * NBUCK_MAX);
    int* sorted_src = (int*)(base + off);      off = align256(off + sizeof(int) * (size_t)E);
    unsigned* binned = (unsigned*)(base + off); off = align256(off + sizeof(unsigned) * (size_t)E);
    unsigned short* xb = (unsigned short*)(base + off);
    off = align256(off + sizeof(short) * (size_t)n * D);
    unsigned short* bufA = (unsigned short*)(base + off);
    off = align256(off + sizeof(short) * (size_t)n * D);
    unsigned short* bufB = (unsigned short*)(base + off);
    off = align256(off + sizeof(short) * (size_t)n * D);
    unsigned short* wf = (unsigned short*)(base + off);

    // ---- CSR build (once; reused by both layers) ----
    hipMemsetAsync(degI, 0, sizeof(int) * (size_t)n, stream);
    const int eblocks = (E + 255) / 256;
    const int nblocks = (n + 255) / 256;
    hist_kernel<<<eblocks, 256, 0, stream>>>(dstI, degI, E);
    scan_blocks<<<nblocks, 256, 0, stream>>>(degI, local, blocksum, n);
    scan_sums<<<1, 1024, 0, stream>>>(blocksum, nblocks);
    finalize_scan<<<(n + 256) / 256, 256, 0, stream>>>(local, blocksum, rowptr,
                                                       gcursor, n, E);
    bin_kernel<<<(E + 4095) / 4096, 256, 0, stream>>>(srcI, dstI, gcursor,
                                                      binned, E, nbuck);
    bucket_sort<<<nbuck, 256, 0, stream>>>(binned, rowptr, sorted_src, n);

    // ---- Weight fragment packing + x conversion ----
    pack_w<<<32, 256, 0, stream>>>(w1l, w1r, w2l, w2r, wf);
    const int n4 = n * (D / 4);
    f32_to_bf16<<<(n4 + 255) / 256, 256, 0, stream>>>(x, xb, n4);

    const int ablocks = (int)(((long long)n * 64 + 255) / 256);
    const int gblocks = (n + 63) / 64;

    // Layer 1
    aggregate_bf16<<<ablocks, 256, 0, stream>>>(xb, sorted_src, rowptr, bufA, n);
    mfma_gemm<<<gblocks, 256, 0, stream>>>(bufA, xb, wf, wf + 16384, b1l, bufA, n);

    // Layer 2
    aggregate_bf16<<<ablocks, 256, 0, stream>>>(bufA, sorted_src, rowptr, bufB, n);
    mfma_gemm<<<gblocks, 256, 0, stream>>>(bufB, bufA, wf + 2 * 16384, wf + 3 * 16384, b2l, bufB, n);

    // Output projection
    const int oblocks = (int)(((long long)n * 32 + 255) / 256);
    out_proj<<<oblocks, 256, 0, stream>>>(bufB, wout, bout, (float*)d_out, n);
}

// Round 8
// 358.532 us; speedup vs baseline: 15.9385x; 1.1862x over previous
//
#include <hip/hip_runtime.h>

constexpr int D = 128;
constexpr int BSHIFT = 9;               // 512 nodes per bucket
constexpr int BNODES = 1 << BSHIFT;
constexpr int NBUCK_MAX = 256;          // n=100000 -> 196 buckets
using short8 = __attribute__((ext_vector_type(8))) short;
using f32x4  = __attribute__((ext_vector_type(4))) float;

__device__ __forceinline__ unsigned rneb(float f) {
    unsigned u = __float_as_uint(f);
    return (u + 0x7fffu + ((u >> 16) & 1u)) >> 16;   // bf16 bits (RNE)
}
__device__ __forceinline__ float lo2f(unsigned u) { return __uint_as_float(u << 16); }
__device__ __forceinline__ float hi2f(unsigned u) { return __uint_as_float(u & 0xffff0000u); }

// ---------------------------------------------------------------------------
__global__ __launch_bounds__(256) void f32_to_bf16(
    const float* __restrict__ in, unsigned short* __restrict__ out, int n4)
{
    int i = blockIdx.x * 256 + threadIdx.x;
    if (i >= n4) return;
    float4 v = reinterpret_cast<const float4*>(in)[i];
    uint2 o;
    o.x = rneb(v.x) | (rneb(v.y) << 16);
    o.y = rneb(v.z) | (rneb(v.w) << 16);
    reinterpret_cast<uint2*>(out)[i] = o;
}

// ---------------------------------------------------------------------------
// Pack the 4 weight matrices [j][k] f32 into bf16 MFMA B-fragments:
// wf[m][f=c*4+ks][lane][i] = W_m[c*16 + (lane&15)][ks*32 + (lane>>4)*8 + i]
__global__ __launch_bounds__(256) void pack_w(
    const float* __restrict__ w1l, const float* __restrict__ w1r,
    const float* __restrict__ w2l, const float* __restrict__ w2r,
    unsigned short* __restrict__ wf)
{
    int t = blockIdx.x * 256 + threadIdx.x;          // 8192 threads
    int m = t >> 11;
    int r = t & 2047;                                 // f*64 + lane
    int f = r >> 6, lane = r & 63;
    int c = f >> 2, ks = f & 3;
    int col = c * 16 + (lane & 15);
    int k0 = ks * 32 + (lane >> 4) * 8;
    const float* W = (m == 0) ? w1l : (m == 1) ? w1r : (m == 2) ? w2l : w2r;
    unsigned short o[8];
#pragma unroll
    for (int i = 0; i < 8; ++i) o[i] = (unsigned short)rneb(W[col * D + k0 + i]);
    uint4 pk;
    pk.x = o[0] | ((unsigned)o[1] << 16);
    pk.y = o[2] | ((unsigned)o[3] << 16);
    pk.z = o[4] | ((unsigned)o[5] << 16);
    pk.w = o[6] | ((unsigned)o[7] << 16);
    reinterpret_cast<uint4*>(wf)[t] = pk;
}

// ---------------------------------------------------------------------------
// Pass 1: per-bucket edge counts (LDS hist per block, 1 global atomic per
// (block,bucket)). No node-granular global atomics anywhere.
__global__ __launch_bounds__(256) void bucket_count(
    const int* __restrict__ dstI, int* __restrict__ bcnt, int E, int nb)
{
    __shared__ int lh[NBUCK_MAX];
    const int t = threadIdx.x;
    const int e0 = blockIdx.x * 4096;
    for (int i = t; i < nb; i += 256) lh[i] = 0;
    __syncthreads();
#pragma unroll
    for (int q = 0; q < 16; ++q) {
        int e = e0 + q * 256 + t;
        if (e < E) atomicAdd(&lh[dstI[e] >> BSHIFT], 1);
    }
    __syncthreads();
    for (int b = t; b < nb; b += 256)
        if (lh[b] > 0) atomicAdd(&bcnt[b], lh[b]);
}

// Pass 2: scan 196 bucket counts -> bucket base offsets + bin cursors.
__global__ __launch_bounds__(256) void bucket_scan(
    const int* __restrict__ bcnt, int* __restrict__ bbase,
    int* __restrict__ gcursor, int nb)
{
    __shared__ int tmp[256];
    const int t = threadIdx.x;
    const int v = (t < nb) ? bcnt[t] : 0;
    tmp[t] = v;
    __syncthreads();
    for (int off = 1; off < 256; off <<= 1) {
        int u = (t >= off) ? tmp[t - off] : 0;
        __syncthreads();
        tmp[t] += u;
        __syncthreads();
    }
    int excl = tmp[t] - v;
    if (t < nb) { bbase[t] = excl; gcursor[t] = excl; }
    if (t == nb - 1) bbase[nb] = excl + v;
}

// Pass 3: bin edges into bucket-contiguous runs. Packed word =
// src | (dst & 511) << 17.   (src < 2^17, n = 100000)
__global__ __launch_bounds__(256) void bin_kernel(
    const int* __restrict__ srcI, const int* __restrict__ dstI,
    int* __restrict__ gcursor, unsigned* __restrict__ binned, int E, int nb)
{
    __shared__ int lhist[NBUCK_MAX];
    __shared__ int lbase[NBUCK_MAX];
    __shared__ int lcnt[NBUCK_MAX];
    const int t = threadIdx.x;
    const int e0 = blockIdx.x * 4096;
    for (int i = t; i < nb; i += 256) { lhist[i] = 0; lcnt[i] = 0; }
    __syncthreads();

    int dcache[16], scache[16];
#pragma unroll
    for (int q = 0; q < 16; ++q) {
        int e = e0 + q * 256 + t;
        int d = (e < E) ? dstI[e] : -1;
        dcache[q] = d;
        scache[q] = (e < E) ? srcI[e] : 0;
        if (d >= 0) atomicAdd(&lhist[d >> BSHIFT], 1);
    }
    __syncthreads();
    for (int b = t; b < nb; b += 256)
        if (lhist[b] > 0) lbase[b] = atomicAdd(&gcursor[b], lhist[b]);
    __syncthreads();
#pragma unroll
    for (int q = 0; q < 16; ++q) {
        int d = dcache[q];
        if (d >= 0) {
            int b = d >> BSHIFT;
            int off = atomicAdd(&lcnt[b], 1);
            binned[lbase[b] + off] =
                (unsigned)scache[q] | ((unsigned)(d & (BNODES - 1)) << 17);
        }
    }
}

// Pass 4: one block per bucket. LDS histogram of the bucket's 512 nodes,
// LDS scan -> rowptr slice, then LDS-cursor scatter -> sorted_src.
__global__ __launch_bounds__(256) void bucket_build(
    const unsigned* __restrict__ binned, const int* __restrict__ bbase,
    int* __restrict__ rowptr, int* __restrict__ sorted_src, int n, int E)
{
    __shared__ int hist[BNODES];
    __shared__ int cur[BNODES];
    __shared__ int tmp[256];
    const int t = threadIdx.x;
    const int b = blockIdx.x;
    const int node0 = b << BSHIFT;
    const int ebeg = bbase[b];
    const int eend = bbase[b + 1];

    hist[t] = 0; hist[t + 256] = 0;
    __syncthreads();
    for (int e = ebeg + t; e < eend; e += 256)
        atomicAdd(&hist[(binned[e] >> 17) & (BNODES - 1)], 1);
    __syncthreads();

    const int v0 = hist[2 * t], v1 = hist[2 * t + 1];
    const int s = v0 + v1;
    tmp[t] = s;
    __syncthreads();
    for (int off = 1; off < 256; off <<= 1) {
        int u = (t >= off) ? tmp[t - off] : 0;
        __syncthreads();
        tmp[t] += u;
        __syncthreads();
    }
    const int pre = ebeg + tmp[t] - s;       // exclusive prefix of node 2t
    const int i0 = node0 + 2 * t, i1 = i0 + 1;
    cur[2 * t] = pre;
    cur[2 * t + 1] = pre + v0;
    if (i0 < n) rowptr[i0] = pre;
    if (i1 < n) rowptr[i1] = pre + v0;
    if (b == 0 && t == 0) rowptr[n] = E;
    __syncthreads();

    for (int e = ebeg + t; e < eend; e += 256) {
        unsigned w = binned[e];
        int pos = atomicAdd(&cur[(w >> 17) & (BNODES - 1)], 1);
        sorted_src[pos] = (int)(w & 0x1FFFF);
    }
}

// ---------------------------------------------------------------------------
// Gather-mean aggregation, wide-load version: one 64-lane wave per node.
// lane = (sub = lane>>4, part = lane&15); each lane loads dwordx4 (16 B =
// 8 bf16) of row src[e+sub] at column slice part*8. Cross-sub reduce via
// shfl_xor(16|32) at the end.
__global__ __launch_bounds__(256) void aggregate_bf16(
    const unsigned short* __restrict__ feat, const int* __restrict__ sorted_src,
    const int* __restrict__ rowptr, unsigned short* __restrict__ outb, int n)
{
    const int wid = (blockIdx.x * 256 + threadIdx.x) >> 6;
    if (wid >= n) return;
    const int lane = threadIdx.x & 63;
    const int sub = lane >> 4;
    const int part = lane & 15;
    const int beg = rowptr[wid];
    const int end = rowptr[wid + 1];
    const int deg = end - beg;

    float acc[8];
#pragma unroll
    for (int j = 0; j < 8; ++j) acc[j] = 0.f;

    int e = beg;
    for (; e + 8 <= end; e += 8) {
        const int s0 = sorted_src[e + sub];
        const int s1 = sorted_src[e + 4 + sub];
        const uint4 v0 = *reinterpret_cast<const uint4*>(feat + (size_t)s0 * D + part * 8);
        const uint4 v1 = *reinterpret_cast<const uint4*>(feat + (size_t)s1 * D + part * 8);
        acc[0] += lo2f(v0.x); acc[1] += hi2f(v0.x);
        acc[2] += lo2f(v0.y); acc[3] += hi2f(v0.y);
        acc[4] += lo2f(v0.z); acc[5] += hi2f(v0.z);
        acc[6] += lo2f(v0.w); acc[7] += hi2f(v0.w);
        acc[0] += lo2f(v1.x); acc[1] += hi2f(v1.x);
        acc[2] += lo2f(v1.y); acc[3] += hi2f(v1.y);
        acc[4] += lo2f(v1.z); acc[5] += hi2f(v1.z);
        acc[6] += lo2f(v1.w); acc[7] += hi2f(v1.w);
    }
    if (e + 4 <= end) {
        const int s0 = sorted_src[e + sub];
        const uint4 v0 = *reinterpret_cast<const uint4*>(feat + (size_t)s0 * D + part * 8);
        acc[0] += lo2f(v0.x); acc[1] += hi2f(v0.x);
        acc[2] += lo2f(v0.y); acc[3] += hi2f(v0.y);
        acc[4] += lo2f(v0.z); acc[5] += hi2f(v0.z);
        acc[6] += lo2f(v0.w); acc[7] += hi2f(v0.w);
        e += 4;
    }
    if (e < end) {
        const int ei = e + sub;
        const bool act = ei < end;
        const int s = act ? sorted_src[ei] : sorted_src[beg];
        const float m = act ? 1.f : 0.f;
        const uint4 v = *reinterpret_cast<const uint4*>(feat + (size_t)s * D + part * 8);
        acc[0] += m * lo2f(v.x); acc[1] += m * hi2f(v.x);
        acc[2] += m * lo2f(v.y); acc[3] += m * hi2f(v.y);
        acc[4] += m * lo2f(v.z); acc[5] += m * hi2f(v.z);
        acc[6] += m * lo2f(v.w); acc[7] += m * hi2f(v.w);
    }

#pragma unroll
    for (int j = 0; j < 8; ++j) {
        acc[j] += __shfl_xor(acc[j], 16);
        acc[j] += __shfl_xor(acc[j], 32);
    }

    if (sub == 0) {
        const float inv = (deg > 0) ? 1.0f / (float)deg : 0.f;
        uint4 pk;
        pk.x = rneb(acc[0] * inv) | (rneb(acc[1] * inv) << 16);
        pk.y = rneb(acc[2] * inv) | (rneb(acc[3] * inv) << 16);
        pk.z = rneb(acc[4] * inv) | (rneb(acc[5] * inv) << 16);
        pk.w = rneb(acc[6] * inv) | (rneb(acc[7] * inv) << 16);
        *reinterpret_cast<uint4*>(outb + (size_t)wid * D + part * 8) = pk;
    }
}

// ---------------------------------------------------------------------------
// Fused SAGE layer via bf16 MFMA (no LDS):
// out[i][j] = relu( mean[i]@WL^T + bL + self[i]@WR^T )  -> bf16
// 4 waves/block, 16 rows/wave, N=128 (8 col-frags), K=128 (4 k-steps).
// outb may alias aMean: each wave reads only its own 16 rows before writing.
__global__ __launch_bounds__(256) void mfma_gemm(
    const unsigned short* __restrict__ aMean, const unsigned short* __restrict__ aSelf,
    const unsigned short* __restrict__ wfL, const unsigned short* __restrict__ wfR,
    const float* __restrict__ bL, unsigned short* __restrict__ outb, int n)
{
    const int lane = threadIdx.x & 63;
    const int wave = threadIdx.x >> 6;
    const int lo = lane & 15, hi = lane >> 4;
    const int row0 = blockIdx.x * 64 + wave * 16;
    int arow = row0 + lo;
    if (arow > n - 1) arow = n - 1;       // clamp stays inside this block's rows
    const size_t abase = (size_t)arow * D;

    f32x4 acc[8];
#pragma unroll
    for (int c = 0; c < 8; ++c) acc[c] = (f32x4){0.f, 0.f, 0.f, 0.f};

#pragma unroll
    for (int p = 0; p < 2; ++p) {
        const unsigned short* A  = p ? aSelf : aMean;
        const unsigned short* WF = p ? wfR : wfL;
#pragma unroll
        for (int ks = 0; ks < 4; ++ks) {
            short8 af = *reinterpret_cast<const short8*>(A + abase + ks * 32 + hi * 8);
#pragma unroll
            for (int c = 0; c < 8; ++c) {
                short8 bf = *reinterpret_cast<const short8*>(
                    WF + ((((c << 2) | ks) * 64 + lane) << 3));
                acc[c] = __builtin_amdgcn_mfma_f32_16x16x32_bf16(af, bf, acc[c], 0, 0, 0);
            }
        }
    }

#pragma unroll
    for (int c = 0; c < 8; ++c) {
        const int col = (c << 4) | lo;
        const float bias = bL[col];
#pragma unroll
        for (int j = 0; j < 4; ++j) {
            const int row = row0 + (hi << 2) + j;
            if (row < n)
                outb[(size_t)row * D + col] =
                    (unsigned short)rneb(fmaxf(acc[c][j] + bias, 0.f));
        }
    }
}

// ---------------------------------------------------------------------------
// out[i][d] = sum_j h2[i][j] * w_out[d][j] + b_out[d]   (d_out = 4), h2 bf16.
__global__ __launch_bounds__(256) void out_proj(
    const unsigned short* __restrict__ h2, const float* __restrict__ w_out,
    const float* __restrict__ b_out, float* __restrict__ out, int n)
{
    __shared__ float wsm[4 * D];
    wsm[threadIdx.x] = w_out[threadIdx.x];
    wsm[threadIdx.x + 256] = w_out[threadIdx.x + 256];
    __syncthreads();

    int t = blockIdx.x * 256 + threadIdx.x;
    int i = t >> 5;
    if (i >= n) return;
    int lane = t & 31;

    uint2 u = *reinterpret_cast<const uint2*>(h2 + (size_t)i * D + lane * 4);
    float h0 = lo2f(u.x), h1 = hi2f(u.x), h2v = lo2f(u.y), h3 = hi2f(u.y);
    float p[4];
#pragma unroll
    for (int d = 0; d < 4; ++d) {
        const float* wr = &wsm[d * D + lane * 4];
        p[d] = h0 * wr[0] + h1 * wr[1] + h2v * wr[2] + h3 * wr[3];
    }
#pragma unroll
    for (int off = 16; off > 0; off >>= 1) {
#pragma unroll
        for (int d = 0; d < 4; ++d) p[d] += __shfl_down(p[d], off, 32);
    }
    if (lane == 0) {
        const float4 b = *reinterpret_cast<const float4*>(b_out);
        float4 o;
        o.x = p[0] + b.x; o.y = p[1] + b.y; o.z = p[2] + b.z; o.w = p[3] + b.w;
        *reinterpret_cast<float4*>(out + (size_t)i * 4) = o;
    }
}

// ---------------------------------------------------------------------------
extern "C" void kernel_launch(void* const* d_in, const int* in_sizes, int n_in,
                              void* d_out, int out_size, void* d_ws, size_t ws_size,
                              hipStream_t stream)
{
    const float* x    = (const float*)d_in[0];
    const int*   ei   = (const int*)  d_in[1];
    const float* w1l  = (const float*)d_in[2];
    const float* b1l  = (const float*)d_in[3];
    const float* w1r  = (const float*)d_in[4];
    const float* w2l  = (const float*)d_in[5];
    const float* b2l  = (const float*)d_in[6];
    const float* w2r  = (const float*)d_in[7];
    const float* wout = (const float*)d_in[8];
    const float* bout = (const float*)d_in[9];

    const int n = in_sizes[0] / D;       // 100000
    const int E = in_sizes[1] / 2;       // 1600000
    const int* srcI = ei;
    const int* dstI = ei + E;
    const int nbuck = (n + BNODES - 1) >> BSHIFT;   // 196

    auto align256 = [](size_t v) { return (v + 255) & ~(size_t)255; };
    char* base = (char*)d_ws;
    size_t off = 0;
    int* bcnt = (int*)(base + off);            off = align256(off + sizeof(int) * NBUCK_MAX);
    int* bbase = (int*)(base + off);           off = align256(off + sizeof(int) * (NBUCK_MAX + 1));
    int* gcursor = (int*)(base + off);         off = align256(off + sizeof(int) * NBUCK_MAX);
    int* rowptr = (int*)(base + off);          off = align256(off + sizeof(int) * (size_t)(n + 1));
    int* sorted_src = (int*)(base + off);      off = align256(off + sizeof(int) * (size_t)E);
    unsigned* binned = (unsigned*)(base + off); off = align256(off + sizeof(unsigned) * (size_t)E);
    unsigned short* xb = (unsigned short*)(base + off);
    off = align256(off + sizeof(short) * (size_t)n * D);
    unsigned short* bufA = (unsigned short*)(base + off);
    off = align256(off + sizeof(short) * (size_t)n * D);
    unsigned short* bufB = (unsigned short*)(base + off);
    off = align256(off + sizeof(short) * (size_t)n * D);
    unsigned short* wf = (unsigned short*)(base + off);

    // ---- CSR build (once; reused by both layers) ----
    hipMemsetAsync(bcnt, 0, sizeof(int) * NBUCK_MAX, stream);
    const int ebblocks = (E + 4095) / 4096;
    bucket_count<<<ebblocks, 256, 0, stream>>>(dstI, bcnt, E, nbuck);
    bucket_scan<<<1, 256, 0, stream>>>(bcnt, bbase, gcursor, nbuck);
    bin_kernel<<<ebblocks, 256, 0, stream>>>(srcI, dstI, gcursor, binned, E, nbuck);
    bucket_build<<<nbuck, 256, 0, stream>>>(binned, bbase, rowptr, sorted_src, n, E);

    // ---- Weight fragment packing + x conversion ----
    pack_w<<<32, 256, 0, stream>>>(w1l, w1r, w2l, w2r, wf);
    const int n4 = n * (D / 4);
    f32_to_bf16<<<(n4 + 255) / 256, 256, 0, stream>>>(x, xb, n4);

    const int ablocks = (int)(((long long)n * 64 + 255) / 256);
    const int gblocks = (n + 63) / 64;

    // Layer 1
    aggregate_bf16<<<ablocks, 256, 0, stream>>>(xb, sorted_src, rowptr, bufA, n);
    mfma_gemm<<<gblocks, 256, 0, stream>>>(bufA, xb, wf, wf + 16384, b1l, bufA, n);

    // Layer 2
    aggregate_bf16<<<ablocks, 256, 0, stream>>>(bufA, sorted_src, rowptr, bufB, n);
    mfma_gemm<<<gblocks, 256, 0, stream>>>(bufB, bufA, wf + 2 * 16384, wf + 3 * 16384, b2l, bufB, n);

    // Output projection
    const int oblocks = (int)(((long long)n * 32 + 255) / 256);
    out_proj<<<oblocks, 256, 0, stream>>>(bufB, wout, bout, (float*)d_out, n);
}

// Round 10
// 356.657 us; speedup vs baseline: 16.0223x; 1.0053x over previous
//
#include <hip/hip_runtime.h>

constexpr int D = 128;
constexpr int BSHIFT = 9;               // 512 nodes per bucket
constexpr int BNODES = 1 << BSHIFT;
constexpr int NBUCK_MAX = 256;          // n=100000 -> 196 buckets
using short8 = __attribute__((ext_vector_type(8))) short;
using f32x4  = __attribute__((ext_vector_type(4))) float;

__device__ __forceinline__ unsigned rneb(float f) {
    unsigned u = __float_as_uint(f);
    return (u + 0x7fffu + ((u >> 16) & 1u)) >> 16;   // bf16 bits (RNE)
}
__device__ __forceinline__ float lo2f(unsigned u) { return __uint_as_float(u << 16); }
__device__ __forceinline__ float hi2f(unsigned u) { return __uint_as_float(u & 0xffff0000u); }

// ---------------------------------------------------------------------------
__global__ __launch_bounds__(256) void f32_to_bf16(
    const float* __restrict__ in, unsigned short* __restrict__ out, int n4)
{
    int i = blockIdx.x * 256 + threadIdx.x;
    if (i >= n4) return;
    float4 v = reinterpret_cast<const float4*>(in)[i];
    uint2 o;
    o.x = rneb(v.x) | (rneb(v.y) << 16);
    o.y = rneb(v.z) | (rneb(v.w) << 16);
    reinterpret_cast<uint2*>(out)[i] = o;
}

// ---------------------------------------------------------------------------
// Pack the 4 weight matrices [j][k] f32 into bf16 MFMA B-fragments:
// wf[m][f=c*4+ks][lane][i] = W_m[c*16 + (lane&15)][ks*32 + (lane>>4)*8 + i]
__global__ __launch_bounds__(256) void pack_w(
    const float* __restrict__ w1l, const float* __restrict__ w1r,
    const float* __restrict__ w2l, const float* __restrict__ w2r,
    unsigned short* __restrict__ wf)
{
    int t = blockIdx.x * 256 + threadIdx.x;          // 8192 threads
    int m = t >> 11;
    int r = t & 2047;                                 // f*64 + lane
    int f = r >> 6, lane = r & 63;
    int c = f >> 2, ks = f & 3;
    int col = c * 16 + (lane & 15);
    int k0 = ks * 32 + (lane >> 4) * 8;
    const float* W = (m == 0) ? w1l : (m == 1) ? w1r : (m == 2) ? w2l : w2r;
    unsigned short o[8];
#pragma unroll
    for (int i = 0; i < 8; ++i) o[i] = (unsigned short)rneb(W[col * D + k0 + i]);
    uint4 pk;
    pk.x = o[0] | ((unsigned)o[1] << 16);
    pk.y = o[2] | ((unsigned)o[3] << 16);
    pk.z = o[4] | ((unsigned)o[5] << 16);
    pk.w = o[6] | ((unsigned)o[7] << 16);
    reinterpret_cast<uint4*>(wf)[t] = pk;
}

// ---------------------------------------------------------------------------
// Pass 1: per-bucket edge counts (LDS hist per block, 1 global atomic per
// (block,bucket)).
__global__ __launch_bounds__(256) void bucket_count(
    const int* __restrict__ dstI, int* __restrict__ bcnt, int E, int nb)
{
    __shared__ int lh[NBUCK_MAX];
    const int t = threadIdx.x;
    const int e0 = blockIdx.x * 4096;
    for (int i = t; i < nb; i += 256) lh[i] = 0;
    __syncthreads();
#pragma unroll
    for (int q = 0; q < 16; ++q) {
        int e = e0 + q * 256 + t;
        if (e < E) atomicAdd(&lh[dstI[e] >> BSHIFT], 1);
    }
    __syncthreads();
    for (int b = t; b < nb; b += 256)
        if (lh[b] > 0) atomicAdd(&bcnt[b], lh[b]);
}

// Pass 2: scan bucket counts -> bucket base offsets + bin cursors.
__global__ __launch_bounds__(256) void bucket_scan(
    const int* __restrict__ bcnt, int* __restrict__ bbase,
    int* __restrict__ gcursor, int nb)
{
    __shared__ int tmp[256];
    const int t = threadIdx.x;
    const int v = (t < nb) ? bcnt[t] : 0;
    tmp[t] = v;
    __syncthreads();
    for (int off = 1; off < 256; off <<= 1) {
        int u = (t >= off) ? tmp[t - off] : 0;
        __syncthreads();
        tmp[t] += u;
        __syncthreads();
    }
    int excl = tmp[t] - v;
    if (t < nb) { bbase[t] = excl; gcursor[t] = excl; }
    if (t == nb - 1) bbase[nb] = excl + v;
}

// Pass 3: bin edges into bucket-contiguous runs. Packed word =
// src | (dst & 511) << 17.   (src < 2^17, n = 100000)
__global__ __launch_bounds__(256) void bin_kernel(
    const int* __restrict__ srcI, const int* __restrict__ dstI,
    int* __restrict__ gcursor, unsigned* __restrict__ binned, int E, int nb)
{
    __shared__ int lhist[NBUCK_MAX];
    __shared__ int lbase[NBUCK_MAX];
    __shared__ int lcnt[NBUCK_MAX];
    const int t = threadIdx.x;
    const int e0 = blockIdx.x * 4096;
    for (int i = t; i < nb; i += 256) { lhist[i] = 0; lcnt[i] = 0; }
    __syncthreads();

    int dcache[16], scache[16];
#pragma unroll
    for (int q = 0; q < 16; ++q) {
        int e = e0 + q * 256 + t;
        int d = (e < E) ? dstI[e] : -1;
        dcache[q] = d;
        scache[q] = (e < E) ? srcI[e] : 0;
        if (d >= 0) atomicAdd(&lhist[d >> BSHIFT], 1);
    }
    __syncthreads();
    for (int b = t; b < nb; b += 256)
        if (lhist[b] > 0) lbase[b] = atomicAdd(&gcursor[b], lhist[b]);
    __syncthreads();
#pragma unroll
    for (int q = 0; q < 16; ++q) {
        int d = dcache[q];
        if (d >= 0) {
            int b = d >> BSHIFT;
            int off = atomicAdd(&lcnt[b], 1);
            binned[lbase[b] + off] =
                (unsigned)scache[q] | ((unsigned)(d & (BNODES - 1)) << 17);
        }
    }
}

// Pass 4: one block per bucket. LDS histogram of the bucket's 512 nodes,
// LDS scan -> rowptr slice, then LDS-cursor scatter -> sorted_src.
__global__ __launch_bounds__(256) void bucket_build(
    const unsigned* __restrict__ binned, const int* __restrict__ bbase,
    int* __restrict__ rowptr, int* __restrict__ sorted_src, int n, int E)
{
    __shared__ int hist[BNODES];
    __shared__ int cur[BNODES];
    __shared__ int tmp[256];
    const int t = threadIdx.x;
    const int b = blockIdx.x;
    const int node0 = b << BSHIFT;
    const int ebeg = bbase[b];
    const int eend = bbase[b + 1];

    hist[t] = 0; hist[t + 256] = 0;
    __syncthreads();
    for (int e = ebeg + t; e < eend; e += 256)
        atomicAdd(&hist[(binned[e] >> 17) & (BNODES - 1)], 1);
    __syncthreads();

    const int v0 = hist[2 * t], v1 = hist[2 * t + 1];
    const int s = v0 + v1;
    tmp[t] = s;
    __syncthreads();
    for (int off = 1; off < 256; off <<= 1) {
        int u = (t >= off) ? tmp[t - off] : 0;
        __syncthreads();
        tmp[t] += u;
        __syncthreads();
    }
    const int pre = ebeg + tmp[t] - s;       // exclusive prefix of node 2t
    const int i0 = node0 + 2 * t, i1 = i0 + 1;
    cur[2 * t] = pre;
    cur[2 * t + 1] = pre + v0;
    if (i0 < n) rowptr[i0] = pre;
    if (i1 < n) rowptr[i1] = pre + v0;
    if (b == 0 && t == 0) rowptr[n] = E;
    __syncthreads();

    for (int e = ebeg + t; e < eend; e += 256) {
        unsigned w = binned[e];
        int pos = atomicAdd(&cur[(w >> 17) & (BNODES - 1)], 1);
        sorted_src[pos] = (int)(w & 0x1FFFF);
    }
}

// ---------------------------------------------------------------------------
// Gather-mean aggregation, wide-load version (round-8 verified math):
// one 64-lane wave per node; lane = (sub = lane>>4, part = lane&15); each
// lane loads dwordx4 (8 bf16) of row src[e+sub] at column slice part*8.
// Cross-sub reduce via shfl_xor(16|32) at the end.
__global__ __launch_bounds__(256) void aggregate_bf16(
    const unsigned short* __restrict__ feat, const int* __restrict__ sorted_src,
    const int* __restrict__ rowptr, unsigned short* __restrict__ outb, int n)
{
    const int wid = (blockIdx.x * 256 + threadIdx.x) >> 6;
    if (wid >= n) return;
    const int lane = threadIdx.x & 63;
    const int sub = lane >> 4;
    const int part = lane & 15;
    const int beg = rowptr[wid];
    const int end = rowptr[wid + 1];
    const int deg = end - beg;

    float acc[8];
#pragma unroll
    for (int j = 0; j < 8; ++j) acc[j] = 0.f;

    int e = beg;
    for (; e + 8 <= end; e += 8) {
        const int s0 = sorted_src[e + sub];
        const int s1 = sorted_src[e + 4 + sub];
        const uint4 v0 = *reinterpret_cast<const uint4*>(feat + (size_t)s0 * D + part * 8);
        const uint4 v1 = *reinterpret_cast<const uint4*>(feat + (size_t)s1 * D + part * 8);
        acc[0] += lo2f(v0.x); acc[1] += hi2f(v0.x);
        acc[2] += lo2f(v0.y); acc[3] += hi2f(v0.y);
        acc[4] += lo2f(v0.z); acc[5] += hi2f(v0.z);
        acc[6] += lo2f(v0.w); acc[7] += hi2f(v0.w);
        acc[0] += lo2f(v1.x); acc[1] += hi2f(v1.x);
        acc[2] += lo2f(v1.y); acc[3] += hi2f(v1.y);
        acc[4] += lo2f(v1.z); acc[5] += hi2f(v1.z);
        acc[6] += lo2f(v1.w); acc[7] += hi2f(v1.w);
    }
    if (e + 4 <= end) {
        const int s0 = sorted_src[e + sub];
        const uint4 v0 = *reinterpret_cast<const uint4*>(feat + (size_t)s0 * D + part * 8);
        acc[0] += lo2f(v0.x); acc[1] += hi2f(v0.x);
        acc[2] += lo2f(v0.y); acc[3] += hi2f(v0.y);
        acc[4] += lo2f(v0.z); acc[5] += hi2f(v0.z);
        acc[6] += lo2f(v0.w); acc[7] += hi2f(v0.w);
        e += 4;
    }
    if (e < end) {
        const int ei = e + sub;
        const bool act = ei < end;
        const int s = act ? sorted_src[ei] : sorted_src[beg];
        const float m = act ? 1.f : 0.f;
        const uint4 v = *reinterpret_cast<const uint4*>(feat + (size_t)s * D + part * 8);
        acc[0] += m * lo2f(v.x); acc[1] += m * hi2f(v.x);
        acc[2] += m * lo2f(v.y); acc[3] += m * hi2f(v.y);
        acc[4] += m * lo2f(v.z); acc[5] += m * hi2f(v.z);
        acc[6] += m * lo2f(v.w); acc[7] += m * hi2f(v.w);
    }

#pragma unroll
    for (int j = 0; j < 8; ++j) {
        acc[j] += __shfl_xor(acc[j], 16);
        acc[j] += __shfl_xor(acc[j], 32);
    }

    if (sub == 0) {
        const float inv = (deg > 0) ? 1.0f / (float)deg : 0.f;
        uint4 pk;
        pk.x = rneb(acc[0] * inv) | (rneb(acc[1] * inv) << 16);
        pk.y = rneb(acc[2] * inv) | (rneb(acc[3] * inv) << 16);
        pk.z = rneb(acc[4] * inv) | (rneb(acc[5] * inv) << 16);
        pk.w = rneb(acc[6] * inv) | (rneb(acc[7] * inv) << 16);
        *reinterpret_cast<uint4*>(outb + (size_t)wid * D + part * 8) = pk;
    }
}

// ---------------------------------------------------------------------------
// Layer-1 fused SAGE via bf16 MFMA (no LDS):
// out[i][j] = relu( mean[i]@WL^T + bL + self[i]@WR^T ) -> bf16
__global__ __launch_bounds__(256) void mfma_gemm(
    const unsigned short* __restrict__ aMean, const unsigned short* __restrict__ aSelf,
    const unsigned short* __restrict__ wfL, const unsigned short* __restrict__ wfR,
    const float* __restrict__ bL, unsigned short* __restrict__ outb, int n)
{
    const int lane = threadIdx.x & 63;
    const int wave = threadIdx.x >> 6;
    const int lo = lane & 15, hi = lane >> 4;
    const int row0 = blockIdx.x * 64 + wave * 16;
    int arow = row0 + lo;
    if (arow > n - 1) arow = n - 1;
    const size_t abase = (size_t)arow * D;

    f32x4 acc[8];
#pragma unroll
    for (int c = 0; c < 8; ++c) acc[c] = (f32x4){0.f, 0.f, 0.f, 0.f};

#pragma unroll
    for (int p = 0; p < 2; ++p) {
        const unsigned short* A  = p ? aSelf : aMean;
        const unsigned short* WF = p ? wfR : wfL;
#pragma unroll
        for (int ks = 0; ks < 4; ++ks) {
            short8 af = *reinterpret_cast<const short8*>(A + abase + ks * 32 + hi * 8);
#pragma unroll
            for (int c = 0; c < 8; ++c) {
                short8 bf = *reinterpret_cast<const short8*>(
                    WF + ((((c << 2) | ks) * 64 + lane) << 3));
                acc[c] = __builtin_amdgcn_mfma_f32_16x16x32_bf16(af, bf, acc[c], 0, 0, 0);
            }
        }
    }

#pragma unroll
    for (int c = 0; c < 8; ++c) {
        const int col = (c << 4) | lo;
        const float bias = bL[col];
#pragma unroll
        for (int j = 0; j < 4; ++j) {
            const int row = row0 + (hi << 2) + j;
            if (row < n)
                outb[(size_t)row * D + col] =
                    (unsigned short)rneb(fmaxf(acc[c][j] + bias, 0.f));
        }
    }
}

// ---------------------------------------------------------------------------
// Layer-2 fused SAGE + output projection:
// h2[i][:] = relu( mean[i]@WL^T + bL + self[i]@WR^T )  (registers, f32)
// out[i][d] = h2[i][:] . w_out[d][:] + b_out[d]        (d_out = 4)
__global__ __launch_bounds__(256) void mfma_gemm_out(
    const unsigned short* __restrict__ aMean, const unsigned short* __restrict__ aSelf,
    const unsigned short* __restrict__ wfL, const unsigned short* __restrict__ wfR,
    const float* __restrict__ bL, const float* __restrict__ w_out,
    const float* __restrict__ b_out, float* __restrict__ outp, int n)
{
    __shared__ float wsm[4 * D];
    wsm[threadIdx.x] = w_out[threadIdx.x];
    wsm[threadIdx.x + 256] = w_out[threadIdx.x + 256];
    __syncthreads();

    const int lane = threadIdx.x & 63;
    const int wave = threadIdx.x >> 6;
    const int lo = lane & 15, hi = lane >> 4;
    const int row0 = blockIdx.x * 64 + wave * 16;
    int arow = row0 + lo;
    if (arow > n - 1) arow = n - 1;
    const size_t abase = (size_t)arow * D;

    f32x4 acc[8];
#pragma unroll
    for (int c = 0; c < 8; ++c) acc[c] = (f32x4){0.f, 0.f, 0.f, 0.f};

#pragma unroll
    for (int p = 0; p < 2; ++p) {
        const unsigned short* A  = p ? aSelf : aMean;
        const unsigned short* WF = p ? wfR : wfL;
#pragma unroll
        for (int ks = 0; ks < 4; ++ks) {
            short8 af = *reinterpret_cast<const short8*>(A + abase + ks * 32 + hi * 8);
#pragma unroll
            for (int c = 0; c < 8; ++c) {
                short8 bf = *reinterpret_cast<const short8*>(
                    WF + ((((c << 2) | ks) * 64 + lane) << 3));
                acc[c] = __builtin_amdgcn_mfma_f32_16x16x32_bf16(af, bf, acc[c], 0, 0, 0);
            }
        }
    }

    // Epilogue: relu + project to 4 dims, reduce across the 16-lane lo group.
    float part[4][4];
#pragma unroll
    for (int j = 0; j < 4; ++j)
#pragma unroll
        for (int d = 0; d < 4; ++d) part[j][d] = 0.f;

#pragma unroll
    for (int c = 0; c < 8; ++c) {
        const int col = (c << 4) | lo;
        const float bias = bL[col];
        const float w0 = wsm[0 * D + col];
        const float w1 = wsm[1 * D + col];
        const float w2 = wsm[2 * D + col];
        const float w3 = wsm[3 * D + col];
#pragma unroll
        for (int j = 0; j < 4; ++j) {
            const float h = fmaxf(acc[c][j] + bias, 0.f);
            part[j][0] += h * w0;
            part[j][1] += h * w1;
            part[j][2] += h * w2;
            part[j][3] += h * w3;
        }
    }

#pragma unroll
    for (int m = 1; m < 16; m <<= 1) {
#pragma unroll
        for (int j = 0; j < 4; ++j)
#pragma unroll
            for (int d = 0; d < 4; ++d)
                part[j][d] += __shfl_xor(part[j][d], m);
    }

    if (lo == 0) {
        const float4 bo = *reinterpret_cast<const float4*>(b_out);
#pragma unroll
        for (int j = 0; j < 4; ++j) {
            const int row = row0 + (hi << 2) + j;
            if (row < n) {
                float4 o;
                o.x = part[j][0] + bo.x;
                o.y = part[j][1] + bo.y;
                o.z = part[j][2] + bo.z;
                o.w = part[j][3] + bo.w;
                *reinterpret_cast<float4*>(outp + (size_t)row * 4) = o;
            }
        }
    }
}

// ---------------------------------------------------------------------------
extern "C" void kernel_launch(void* const* d_in, const int* in_sizes, int n_in,
                              void* d_out, int out_size, void* d_ws, size_t ws_size,
                              hipStream_t stream)
{
    const float* x    = (const float*)d_in[0];
    const int*   ei   = (const int*)  d_in[1];
    const float* w1l  = (const float*)d_in[2];
    const float* b1l  = (const float*)d_in[3];
    const float* w1r  = (const float*)d_in[4];
    const float* w2l  = (const float*)d_in[5];
    const float* b2l  = (const float*)d_in[6];
    const float* w2r  = (const float*)d_in[7];
    const float* wout = (const float*)d_in[8];
    const float* bout = (const float*)d_in[9];

    const int n = in_sizes[0] / D;       // 100000
    const int E = in_sizes[1] / 2;       // 1600000
    const int* srcI = ei;
    const int* dstI = ei + E;
    const int nbuck = (n + BNODES - 1) >> BSHIFT;   // 196

    auto align256 = [](size_t v) { return (v + 255) & ~(size_t)255; };
    char* base = (char*)d_ws;
    size_t off = 0;
    int* bcnt = (int*)(base + off);            off = align256(off + sizeof(int) * NBUCK_MAX);
    int* bbase = (int*)(base + off);           off = align256(off + sizeof(int) * (NBUCK_MAX + 1));
    int* gcursor = (int*)(base + off);         off = align256(off + sizeof(int) * NBUCK_MAX);
    int* rowptr = (int*)(base + off);          off = align256(off + sizeof(int) * (size_t)(n + 1));
    int* sorted_src = (int*)(base + off);      off = align256(off + sizeof(int) * (size_t)E);
    unsigned* binned = (unsigned*)(base + off); off = align256(off + sizeof(unsigned) * (size_t)E);
    unsigned short* xb = (unsigned short*)(base + off);
    off = align256(off + sizeof(short) * (size_t)n * D);
    unsigned short* bufA = (unsigned short*)(base + off);
    off = align256(off + sizeof(short) * (size_t)n * D);
    unsigned short* bufB = (unsigned short*)(base + off);
    off = align256(off + sizeof(short) * (size_t)n * D);
    unsigned short* wf = (unsigned short*)(base + off);

    // ---- CSR build (once; reused by both layers) ----
    hipMemsetAsync(bcnt, 0, sizeof(int) * NBUCK_MAX, stream);
    const int ebblocks = (E + 4095) / 4096;
    bucket_count<<<ebblocks, 256, 0, stream>>>(dstI, bcnt, E, nbuck);
    bucket_scan<<<1, 256, 0, stream>>>(bcnt, bbase, gcursor, nbuck);
    bin_kernel<<<ebblocks, 256, 0, stream>>>(srcI, dstI, gcursor, binned, E, nbuck);
    bucket_build<<<nbuck, 256, 0, stream>>>(binned, bbase, rowptr, sorted_src, n, E);

    // ---- Weight fragment packing + x conversion ----
    pack_w<<<32, 256, 0, stream>>>(w1l, w1r, w2l, w2r, wf);
    const int n4 = n * (D / 4);
    f32_to_bf16<<<(n4 + 255) / 256, 256, 0, stream>>>(x, xb, n4);

    const int ablocks = (int)(((long long)n * 64 + 255) / 256);
    const int gblocks = (n + 63) / 64;

    // Layer 1
    aggregate_bf16<<<ablocks, 256, 0, stream>>>(xb, sorted_src, rowptr, bufA, n);
    mfma_gemm<<<gblocks, 256, 0, stream>>>(bufA, xb, wf, wf + 16384, b1l, bufA, n);

    // Layer 2 (+ fused output projection)
    aggregate_bf16<<<ablocks, 256, 0, stream>>>(bufA, sorted_src, rowptr, bufB, n);
    mfma_gemm_out<<<gblocks, 256, 0, stream>>>(bufB, bufA, wf + 2 * 16384, wf + 3 * 16384,
                                               b2l, wout, bout, (float*)d_out, n);
}

// Round 12
// 353.022 us; speedup vs baseline: 16.1873x; 1.0103x over previous
//
#include <hip/hip_runtime.h>

constexpr int D = 128;
constexpr int BSHIFT = 9;               // 512 nodes per bucket
constexpr int BNODES = 1 << BSHIFT;
constexpr int NBUCK_MAX = 256;          // n=100000 -> 196 buckets
using short8 = __attribute__((ext_vector_type(8))) short;
using f32x4  = __attribute__((ext_vector_type(4))) float;

__device__ __forceinline__ unsigned rneb(float f) {
    unsigned u = __float_as_uint(f);
    return (u + 0x7fffu + ((u >> 16) & 1u)) >> 16;   // bf16 bits (RNE)
}
__device__ __forceinline__ float lo2f(unsigned u) { return __uint_as_float(u << 16); }
__device__ __forceinline__ float hi2f(unsigned u) { return __uint_as_float(u & 0xffff0000u); }

// ---------------------------------------------------------------------------
// Fused housekeeping: blocks [0,32) pack weight fragments; block 32 also
// zeroes bcnt; blocks [32, 32+12500) convert x to bf16.
// pack: wf[m][f=c*4+ks][lane][i] = W_m[c*16 + (lane&15)][ks*32 + (lane>>4)*8 + i]
__global__ __launch_bounds__(256) void misc_kernel(
    const float* __restrict__ w1l, const float* __restrict__ w1r,
    const float* __restrict__ w2l, const float* __restrict__ w2r,
    unsigned short* __restrict__ wf,
    const float* __restrict__ x, unsigned short* __restrict__ xb, int n4,
    int* __restrict__ bcnt)
{
    if (blockIdx.x < 32) {
        int t = blockIdx.x * 256 + threadIdx.x;          // 8192 threads
        int m = t >> 11;
        int r = t & 2047;                                 // f*64 + lane
        int f = r >> 6, lane = r & 63;
        int c = f >> 2, ks = f & 3;
        int col = c * 16 + (lane & 15);
        int k0 = ks * 32 + (lane >> 4) * 8;
        const float* W = (m == 0) ? w1l : (m == 1) ? w1r : (m == 2) ? w2l : w2r;
        unsigned short o[8];
#pragma unroll
        for (int i = 0; i < 8; ++i) o[i] = (unsigned short)rneb(W[col * D + k0 + i]);
        uint4 pk;
        pk.x = o[0] | ((unsigned)o[1] << 16);
        pk.y = o[2] | ((unsigned)o[3] << 16);
        pk.z = o[4] | ((unsigned)o[5] << 16);
        pk.w = o[6] | ((unsigned)o[7] << 16);
        reinterpret_cast<uint4*>(wf)[t] = pk;
        return;
    }
    if (blockIdx.x == 32) bcnt[threadIdx.x] = 0;          // NBUCK_MAX == 256
    int i = (blockIdx.x - 32) * 256 + threadIdx.x;
    if (i >= n4) return;
    float4 v = reinterpret_cast<const float4*>(x)[i];
    uint2 o;
    o.x = rneb(v.x) | (rneb(v.y) << 16);
    o.y = rneb(v.z) | (rneb(v.w) << 16);
    reinterpret_cast<uint2*>(xb)[i] = o;
}

// ---------------------------------------------------------------------------
// Pass 1: per-bucket edge counts (LDS hist per block, 1 global atomic per
// (block,bucket)).
__global__ __launch_bounds__(256) void bucket_count(
    const int* __restrict__ dstI, int* __restrict__ bcnt, int E, int nb)
{
    __shared__ int lh[NBUCK_MAX];
    const int t = threadIdx.x;
    const int e0 = blockIdx.x * 4096;
    for (int i = t; i < nb; i += 256) lh[i] = 0;
    __syncthreads();
#pragma unroll
    for (int q = 0; q < 16; ++q) {
        int e = e0 + q * 256 + t;
        if (e < E) atomicAdd(&lh[dstI[e] >> BSHIFT], 1);
    }
    __syncthreads();
    for (int b = t; b < nb; b += 256)
        if (lh[b] > 0) atomicAdd(&bcnt[b], lh[b]);
}

// Pass 2: scan bucket counts -> bucket base offsets + bin cursors.
__global__ __launch_bounds__(256) void bucket_scan(
    const int* __restrict__ bcnt, int* __restrict__ bbase,
    int* __restrict__ gcursor, int nb)
{
    __shared__ int tmp[256];
    const int t = threadIdx.x;
    const int v = (t < nb) ? bcnt[t] : 0;
    tmp[t] = v;
    __syncthreads();
    for (int off = 1; off < 256; off <<= 1) {
        int u = (t >= off) ? tmp[t - off] : 0;
        __syncthreads();
        tmp[t] += u;
        __syncthreads();
    }
    int excl = tmp[t] - v;
    if (t < nb) { bbase[t] = excl; gcursor[t] = excl; }
    if (t == nb - 1) bbase[nb] = excl + v;
}

// Pass 3: bin edges into bucket-contiguous runs. Packed word =
// src | (dst & 511) << 17.   (src < 2^17, n = 100000)
__global__ __launch_bounds__(256) void bin_kernel(
    const int* __restrict__ srcI, const int* __restrict__ dstI,
    int* __restrict__ gcursor, unsigned* __restrict__ binned, int E, int nb)
{
    __shared__ int lhist[NBUCK_MAX];
    __shared__ int lbase[NBUCK_MAX];
    __shared__ int lcnt[NBUCK_MAX];
    const int t = threadIdx.x;
    const int e0 = blockIdx.x * 4096;
    for (int i = t; i < nb; i += 256) { lhist[i] = 0; lcnt[i] = 0; }
    __syncthreads();

    int dcache[16], scache[16];
#pragma unroll
    for (int q = 0; q < 16; ++q) {
        int e = e0 + q * 256 + t;
        int d = (e < E) ? dstI[e] : -1;
        dcache[q] = d;
        scache[q] = (e < E) ? srcI[e] : 0;
        if (d >= 0) atomicAdd(&lhist[d >> BSHIFT], 1);
    }
    __syncthreads();
    for (int b = t; b < nb; b += 256)
        if (lhist[b] > 0) lbase[b] = atomicAdd(&gcursor[b], lhist[b]);
    __syncthreads();
#pragma unroll
    for (int q = 0; q < 16; ++q) {
        int d = dcache[q];
        if (d >= 0) {
            int b = d >> BSHIFT;
            int off = atomicAdd(&lcnt[b], 1);
            binned[lbase[b] + off] =
                (unsigned)scache[q] | ((unsigned)(d & (BNODES - 1)) << 17);
        }
    }
}

// Pass 4: one block per bucket. LDS histogram of the bucket's 512 nodes,
// LDS scan -> rowptr slice, then LDS-cursor scatter -> sorted_src.
__global__ __launch_bounds__(256) void bucket_build(
    const unsigned* __restrict__ binned, const int* __restrict__ bbase,
    int* __restrict__ rowptr, int* __restrict__ sorted_src, int n, int E)
{
    __shared__ int hist[BNODES];
    __shared__ int cur[BNODES];
    __shared__ int tmp[256];
    const int t = threadIdx.x;
    const int b = blockIdx.x;
    const int node0 = b << BSHIFT;
    const int ebeg = bbase[b];
    const int eend = bbase[b + 1];

    hist[t] = 0; hist[t + 256] = 0;
    __syncthreads();
    for (int e = ebeg + t; e < eend; e += 256)
        atomicAdd(&hist[(binned[e] >> 17) & (BNODES - 1)], 1);
    __syncthreads();

    const int v0 = hist[2 * t], v1 = hist[2 * t + 1];
    const int s = v0 + v1;
    tmp[t] = s;
    __syncthreads();
    for (int off = 1; off < 256; off <<= 1) {
        int u = (t >= off) ? tmp[t - off] : 0;
        __syncthreads();
        tmp[t] += u;
        __syncthreads();
    }
    const int pre = ebeg + tmp[t] - s;       // exclusive prefix of node 2t
    const int i0 = node0 + 2 * t, i1 = i0 + 1;
    cur[2 * t] = pre;
    cur[2 * t + 1] = pre + v0;
    if (i0 < n) rowptr[i0] = pre;
    if (i1 < n) rowptr[i1] = pre + v0;
    if (b == 0 && t == 0) rowptr[n] = E;
    __syncthreads();

    for (int e = ebeg + t; e < eend; e += 256) {
        unsigned w = binned[e];
        int pos = atomicAdd(&cur[(w >> 17) & (BNODES - 1)], 1);
        sorted_src[pos] = (int)(w & 0x1FFFF);
    }
}

// ---------------------------------------------------------------------------
// Gather-mean aggregation: one 64-lane wave per node; lane = (sub = lane>>4,
// part = lane&15); each lane loads dwordx4 (8 bf16) of row src[e+sub] at
// column slice part*8. 16-edge main loop keeps 4 feature loads in flight.
// Cross-sub reduce via shfl_xor(16|32) at the end.
__global__ __launch_bounds__(256) void aggregate_bf16(
    const unsigned short* __restrict__ feat, const int* __restrict__ sorted_src,
    const int* __restrict__ rowptr, unsigned short* __restrict__ outb, int n)
{
    const int wid = (blockIdx.x * 256 + threadIdx.x) >> 6;
    if (wid >= n) return;
    const int lane = threadIdx.x & 63;
    const int sub = lane >> 4;
    const int part = lane & 15;
    const int beg = rowptr[wid];
    const int end = rowptr[wid + 1];
    const int deg = end - beg;

    float acc[8];
#pragma unroll
    for (int j = 0; j < 8; ++j) acc[j] = 0.f;

    int e = beg;
    // 16 edges per iteration: 4 independent dwordx4 streams in flight.
    for (; e + 16 <= end; e += 16) {
        const int s0 = sorted_src[e + sub];
        const int s1 = sorted_src[e + 4 + sub];
        const int s2 = sorted_src[e + 8 + sub];
        const int s3 = sorted_src[e + 12 + sub];
        const uint4 v0 = *reinterpret_cast<const uint4*>(feat + (size_t)s0 * D + part * 8);
        const uint4 v1 = *reinterpret_cast<const uint4*>(feat + (size_t)s1 * D + part * 8);
        const uint4 v2 = *reinterpret_cast<const uint4*>(feat + (size_t)s2 * D + part * 8);
        const uint4 v3 = *reinterpret_cast<const uint4*>(feat + (size_t)s3 * D + part * 8);
        acc[0] += lo2f(v0.x); acc[1] += hi2f(v0.x);
        acc[2] += lo2f(v0.y); acc[3] += hi2f(v0.y);
        acc[4] += lo2f(v0.z); acc[5] += hi2f(v0.z);
        acc[6] += lo2f(v0.w); acc[7] += hi2f(v0.w);
        acc[0] += lo2f(v1.x); acc[1] += hi2f(v1.x);
        acc[2] += lo2f(v1.y); acc[3] += hi2f(v1.y);
        acc[4] += lo2f(v1.z); acc[5] += hi2f(v1.z);
        acc[6] += lo2f(v1.w); acc[7] += hi2f(v1.w);
        acc[0] += lo2f(v2.x); acc[1] += hi2f(v2.x);
        acc[2] += lo2f(v2.y); acc[3] += hi2f(v2.y);
        acc[4] += lo2f(v2.z); acc[5] += hi2f(v2.z);
        acc[6] += lo2f(v2.w); acc[7] += hi2f(v2.w);
        acc[0] += lo2f(v3.x); acc[1] += hi2f(v3.x);
        acc[2] += lo2f(v3.y); acc[3] += hi2f(v3.y);
        acc[4] += lo2f(v3.z); acc[5] += hi2f(v3.z);
        acc[6] += lo2f(v3.w); acc[7] += hi2f(v3.w);
    }
    if (e + 8 <= end) {
        const int s0 = sorted_src[e + sub];
        const int s1 = sorted_src[e + 4 + sub];
        const uint4 v0 = *reinterpret_cast<const uint4*>(feat + (size_t)s0 * D + part * 8);
        const uint4 v1 = *reinterpret_cast<const uint4*>(feat + (size_t)s1 * D + part * 8);
        acc[0] += lo2f(v0.x); acc[1] += hi2f(v0.x);
        acc[2] += lo2f(v0.y); acc[3] += hi2f(v0.y);
        acc[4] += lo2f(v0.z); acc[5] += hi2f(v0.z);
        acc[6] += lo2f(v0.w); acc[7] += hi2f(v0.w);
        acc[0] += lo2f(v1.x); acc[1] += hi2f(v1.x);
        acc[2] += lo2f(v1.y); acc[3] += hi2f(v1.y);
        acc[4] += lo2f(v1.z); acc[5] += hi2f(v1.z);
        acc[6] += lo2f(v1.w); acc[7] += hi2f(v1.w);
        e += 8;
    }
    if (e + 4 <= end) {
        const int s0 = sorted_src[e + sub];
        const uint4 v0 = *reinterpret_cast<const uint4*>(feat + (size_t)s0 * D + part * 8);
        acc[0] += lo2f(v0.x); acc[1] += hi2f(v0.x);
        acc[2] += lo2f(v0.y); acc[3] += hi2f(v0.y);
        acc[4] += lo2f(v0.z); acc[5] += hi2f(v0.z);
        acc[6] += lo2f(v0.w); acc[7] += hi2f(v0.w);
        e += 4;
    }
    if (e < end) {
        const int ei = e + sub;
        const bool act = ei < end;
        const int s = act ? sorted_src[ei] : sorted_src[beg];
        const float m = act ? 1.f : 0.f;
        const uint4 v = *reinterpret_cast<const uint4*>(feat + (size_t)s * D + part * 8);
        acc[0] += m * lo2f(v.x); acc[1] += m * hi2f(v.x);
        acc[2] += m * lo2f(v.y); acc[3] += m * hi2f(v.y);
        acc[4] += m * lo2f(v.z); acc[5] += m * hi2f(v.z);
        acc[6] += m * lo2f(v.w); acc[7] += m * hi2f(v.w);
    }

#pragma unroll
    for (int j = 0; j < 8; ++j) {
        acc[j] += __shfl_xor(acc[j], 16);
        acc[j] += __shfl_xor(acc[j], 32);
    }

    if (sub == 0) {
        const float inv = (deg > 0) ? 1.0f / (float)deg : 0.f;
        uint4 pk;
        pk.x = rneb(acc[0] * inv) | (rneb(acc[1] * inv) << 16);
        pk.y = rneb(acc[2] * inv) | (rneb(acc[3] * inv) << 16);
        pk.z = rneb(acc[4] * inv) | (rneb(acc[5] * inv) << 16);
        pk.w = rneb(acc[6] * inv) | (rneb(acc[7] * inv) << 16);
        *reinterpret_cast<uint4*>(outb + (size_t)wid * D + part * 8) = pk;
    }
}

// ---------------------------------------------------------------------------
// Layer-1 fused SAGE via bf16 MFMA (no LDS):
// out[i][j] = relu( mean[i]@WL^T + bL + self[i]@WR^T ) -> bf16
__global__ __launch_bounds__(256) void mfma_gemm(
    const unsigned short* __restrict__ aMean, const unsigned short* __restrict__ aSelf,
    const unsigned short* __restrict__ wfL, const unsigned short* __restrict__ wfR,
    const float* __restrict__ bL, unsigned short* __restrict__ outb, int n)
{
    const int lane = threadIdx.x & 63;
    const int wave = threadIdx.x >> 6;
    const int lo = lane & 15, hi = lane >> 4;
    const int row0 = blockIdx.x * 64 + wave * 16;
    int arow = row0 + lo;
    if (arow > n - 1) arow = n - 1;
    const size_t abase = (size_t)arow * D;

    f32x4 acc[8];
#pragma unroll
    for (int c = 0; c < 8; ++c) acc[c] = (f32x4){0.f, 0.f, 0.f, 0.f};

#pragma unroll
    for (int p = 0; p < 2; ++p) {
        const unsigned short* A  = p ? aSelf : aMean;
        const unsigned short* WF = p ? wfR : wfL;
#pragma unroll
        for (int ks = 0; ks < 4; ++ks) {
            short8 af = *reinterpret_cast<const short8*>(A + abase + ks * 32 + hi * 8);
#pragma unroll
            for (int c = 0; c < 8; ++c) {
                short8 bf = *reinterpret_cast<const short8*>(
                    WF + ((((c << 2) | ks) * 64 + lane) << 3));
                acc[c] = __builtin_amdgcn_mfma_f32_16x16x32_bf16(af, bf, acc[c], 0, 0, 0);
            }
        }
    }

#pragma unroll
    for (int c = 0; c < 8; ++c) {
        const int col = (c << 4) | lo;
        const float bias = bL[col];
#pragma unroll
        for (int j = 0; j < 4; ++j) {
            const int row = row0 + (hi << 2) + j;
            if (row < n)
                outb[(size_t)row * D + col] =
                    (unsigned short)rneb(fmaxf(acc[c][j] + bias, 0.f));
        }
    }
}

// ---------------------------------------------------------------------------
// Layer-2 fused SAGE + output projection:
// h2[i][:] = relu( mean[i]@WL^T + bL + self[i]@WR^T )  (registers, f32)
// out[i][d] = h2[i][:] . w_out[d][:] + b_out[d]        (d_out = 4)
__global__ __launch_bounds__(256) void mfma_gemm_out(
    const unsigned short* __restrict__ aMean, const unsigned short* __restrict__ aSelf,
    const unsigned short* __restrict__ wfL, const unsigned short* __restrict__ wfR,
    const float* __restrict__ bL, const float* __restrict__ w_out,
    const float* __restrict__ b_out, float* __restrict__ outp, int n)
{
    __shared__ float wsm[4 * D];
    wsm[threadIdx.x] = w_out[threadIdx.x];
    wsm[threadIdx.x + 256] = w_out[threadIdx.x + 256];
    __syncthreads();

    const int lane = threadIdx.x & 63;
    const int wave = threadIdx.x >> 6;
    const int lo = lane & 15, hi = lane >> 4;
    const int row0 = blockIdx.x * 64 + wave * 16;
    int arow = row0 + lo;
    if (arow > n - 1) arow = n - 1;
    const size_t abase = (size_t)arow * D;

    f32x4 acc[8];
#pragma unroll
    for (int c = 0; c < 8; ++c) acc[c] = (f32x4){0.f, 0.f, 0.f, 0.f};

#pragma unroll
    for (int p = 0; p < 2; ++p) {
        const unsigned short* A  = p ? aSelf : aMean;
        const unsigned short* WF = p ? wfR : wfL;
#pragma unroll
        for (int ks = 0; ks < 4; ++ks) {
            short8 af = *reinterpret_cast<const short8*>(A + abase + ks * 32 + hi * 8);
#pragma unroll
            for (int c = 0; c < 8; ++c) {
                short8 bf = *reinterpret_cast<const short8*>(
                    WF + ((((c << 2) | ks) * 64 + lane) << 3));
                acc[c] = __builtin_amdgcn_mfma_f32_16x16x32_bf16(af, bf, acc[c], 0, 0, 0);
            }
        }
    }

    // Epilogue: relu + project to 4 dims, reduce across the 16-lane lo group.
    float part[4][4];
#pragma unroll
    for (int j = 0; j < 4; ++j)
#pragma unroll
        for (int d = 0; d < 4; ++d) part[j][d] = 0.f;

#pragma unroll
    for (int c = 0; c < 8; ++c) {
        const int col = (c << 4) | lo;
        const float bias = bL[col];
        const float w0 = wsm[0 * D + col];
        const float w1 = wsm[1 * D + col];
        const float w2 = wsm[2 * D + col];
        const float w3 = wsm[3 * D + col];
#pragma unroll
        for (int j = 0; j < 4; ++j) {
            const float h = fmaxf(acc[c][j] + bias, 0.f);
            part[j][0] += h * w0;
            part[j][1] += h * w1;
            part[j][2] += h * w2;
            part[j][3] += h * w3;
        }
    }

#pragma unroll
    for (int m = 1; m < 16; m <<= 1) {
#pragma unroll
        for (int j = 0; j < 4; ++j)
#pragma unroll
            for (int d = 0; d < 4; ++d)
                part[j][d] += __shfl_xor(part[j][d], m);
    }

    if (lo == 0) {
        const float4 bo = *reinterpret_cast<const float4*>(b_out);
#pragma unroll
        for (int j = 0; j < 4; ++j) {
            const int row = row0 + (hi << 2) + j;
            if (row < n) {
                float4 o;
                o.x = part[j][0] + bo.x;
                o.y = part[j][1] + bo.y;
                o.z = part[j][2] + bo.z;
                o.w = part[j][3] + bo.w;
                *reinterpret_cast<float4*>(outp + (size_t)row * 4) = o;
            }
        }
    }
}

// ---------------------------------------------------------------------------
extern "C" void kernel_launch(void* const* d_in, const int* in_sizes, int n_in,
                              void* d_out, int out_size, void* d_ws, size_t ws_size,
                              hipStream_t stream)
{
    const float* x    = (const float*)d_in[0];
    const int*   ei   = (const int*)  d_in[1];
    const float* w1l  = (const float*)d_in[2];
    const float* b1l  = (const float*)d_in[3];
    const float* w1r  = (const float*)d_in[4];
    const float* w2l  = (const float*)d_in[5];
    const float* b2l  = (const float*)d_in[6];
    const float* w2r  = (const float*)d_in[7];
    const float* wout = (const float*)d_in[8];
    const float* bout = (const float*)d_in[9];

    const int n = in_sizes[0] / D;       // 100000
    const int E = in_sizes[1] / 2;       // 1600000
    const int* srcI = ei;
    const int* dstI = ei + E;
    const int nbuck = (n + BNODES - 1) >> BSHIFT;   // 196

    auto align256 = [](size_t v) { return (v + 255) & ~(size_t)255; };
    char* base = (char*)d_ws;
    size_t off = 0;
    int* bcnt = (int*)(base + off);            off = align256(off + sizeof(int) * NBUCK_MAX);
    int* bbase = (int*)(base + off);           off = align256(off + sizeof(int) * (NBUCK_MAX + 1));
    int* gcursor = (int*)(base + off);         off = align256(off + sizeof(int) * NBUCK_MAX);
    int* rowptr = (int*)(base + off);          off = align256(off + sizeof(int) * (size_t)(n + 1));
    int* sorted_src = (int*)(base + off);      off = align256(off + sizeof(int) * (size_t)E);
    unsigned* binned = (unsigned*)(base + off); off = align256(off + sizeof(unsigned) * (size_t)E);
    unsigned short* xb = (unsigned short*)(base + off);
    off = align256(off + sizeof(short) * (size_t)n * D);
    unsigned short* bufA = (unsigned short*)(base + off);
    off = align256(off + sizeof(short) * (size_t)n * D);
    unsigned short* bufB = (unsigned short*)(base + off);
    off = align256(off + sizeof(short) * (size_t)n * D);
    unsigned short* wf = (unsigned short*)(base + off);

    // ---- Housekeeping first: pack weights, convert x, zero bcnt ----
    const int n4 = n * (D / 4);
    const int cvtblocks = (n4 + 255) / 256;
    misc_kernel<<<32 + cvtblocks, 256, 0, stream>>>(w1l, w1r, w2l, w2r, wf,
                                                    x, xb, n4, bcnt);

    // ---- CSR build (once; reused by both layers) ----
    const int ebblocks = (E + 4095) / 4096;
    bucket_count<<<ebblocks, 256, 0, stream>>>(dstI, bcnt, E, nbuck);
    bucket_scan<<<1, 256, 0, stream>>>(bcnt, bbase, gcursor, nbuck);
    bin_kernel<<<ebblocks, 256, 0, stream>>>(srcI, dstI, gcursor, binned, E, nbuck);
    bucket_build<<<nbuck, 256, 0, stream>>>(binned, bbase, rowptr, sorted_src, n, E);

    const int ablocks = (int)(((long long)n * 64 + 255) / 256);
    const int gblocks = (n + 63) / 64;

    // Layer 1
    aggregate_bf16<<<ablocks, 256, 0, stream>>>(xb, sorted_src, rowptr, bufA, n);
    mfma_gemm<<<gblocks, 256, 0, stream>>>(bufA, xb, wf, wf + 16384, b1l, bufA, n);

    // Layer 2 (+ fused output projection)
    aggregate_bf16<<<ablocks, 256, 0, stream>>>(bufA, sorted_src, rowptr, bufB, n);
    mfma_gemm_out<<<gblocks, 256, 0, stream>>>(bufB, bufA, wf + 2 * 16384, wf + 3 * 16384,
                                               b2l, wout, bout, (float*)d_out, n);
}